// Round 1
// baseline (1308.689 us; speedup 1.0000x reference)
//
#include <hip/hip_runtime.h>
#include <math.h>

#define NN 51200
#define NE 2048000
#define F 128

__device__ __forceinline__ float mish_f(float x) {
  if (x > 20.0f) return x;
  float e = __expf(x);
  float w = 1.0f + e;
  w = w * w;
  return x * (w - 1.0f) / (w + 1.0f);
}

// ---- degree + in-degree count -------------------------------------------
__global__ void k_edge_deg(const int* __restrict__ ei, const float* __restrict__ ew,
                           float* __restrict__ deg, int* __restrict__ cnt) {
  int e = blockIdx.x * blockDim.x + threadIdx.x;
  if (e < NE) {
    int c = ei[NE + e];
    atomicAdd(&deg[c], ew[e]);
    atomicAdd(&cnt[c], 1);
  }
}

__global__ void k_dinv(float* __restrict__ deg) {
  int i = blockIdx.x * blockDim.x + threadIdx.x;
  if (i < NN) deg[i] = rsqrtf(deg[i] + 1.0f);  // +1 = self-loop weight
}

// ---- hierarchical exclusive scan of cnt -> rowptr, cursor ----------------
__global__ __launch_bounds__(256) void k_scan1(const int* __restrict__ cnt, int* __restrict__ bsum) {
  int i = blockIdx.x * 256 + threadIdx.x;
  int s = cnt[i];
#pragma unroll
  for (int off = 1; off < 64; off <<= 1) s += __shfl_xor(s, off);
  __shared__ int wsum[4];
  if ((threadIdx.x & 63) == 0) wsum[threadIdx.x >> 6] = s;
  __syncthreads();
  if (threadIdx.x == 0) bsum[blockIdx.x] = wsum[0] + wsum[1] + wsum[2] + wsum[3];
}

__global__ __launch_bounds__(256) void k_scan2(const int* __restrict__ bsum, int* __restrict__ boff,
                                               int* __restrict__ rowptr) {
  int t = threadIdx.x;
  int lane = t & 63, wid = t >> 6;
  int v = (t < 200) ? bsum[t] : 0;
  int x = v;
#pragma unroll
  for (int off = 1; off < 64; off <<= 1) {
    int y = __shfl_up(x, off);
    if (lane >= off) x += y;
  }
  __shared__ int ws4[4];
  if (lane == 63) ws4[wid] = x;
  __syncthreads();
  int woff = 0;
  for (int k = 0; k < wid; ++k) woff += ws4[k];
  if (t < 200) boff[t] = woff + x - v;
  if (t == 255) rowptr[NN] = woff + x;  // grand total
}

__global__ __launch_bounds__(256) void k_scan3(const int* __restrict__ cnt, const int* __restrict__ boff,
                                               int* __restrict__ rowptr, int* __restrict__ cursor) {
  int i = blockIdx.x * 256 + threadIdx.x;
  int t = threadIdx.x;
  int lane = t & 63, wid = t >> 6;
  int v = cnt[i];
  int x = v;
#pragma unroll
  for (int off = 1; off < 64; off <<= 1) {
    int y = __shfl_up(x, off);
    if (lane >= off) x += y;
  }
  __shared__ int ws4[4];
  if (lane == 63) ws4[wid] = x;
  __syncthreads();
  int woff = boff[blockIdx.x];
  for (int k = 0; k < wid; ++k) woff += ws4[k];
  int excl = woff + x - v;
  rowptr[i] = excl;
  cursor[i] = excl;
}

// ---- CSR fill: edge -> (src,norm) bucketed by dst ------------------------
__global__ void k_fill(const int* __restrict__ ei, const float* __restrict__ ew,
                       const float* __restrict__ dinv, int* __restrict__ cursor,
                       int* __restrict__ csrc, float* __restrict__ cw) {
  int e = blockIdx.x * blockDim.x + threadIdx.x;
  if (e < NE) {
    int r = ei[e], c = ei[NE + e];
    int p = atomicAdd(&cursor[c], 1);
    csrc[p] = r;
    cw[p] = dinv[r] * ew[e] * dinv[c];
  }
}

// ---- fp32 GEMM: C[M,128] = A[M,K] @ W[K,128], 128x128 tile, 8x8/thread ---
__global__ __launch_bounds__(256) void k_gemm(const float* __restrict__ A, const float* __restrict__ W,
                                              float* __restrict__ C, int M, int K) {
  __shared__ float xs[8][128];  // transposed A tile: xs[k][m]
  __shared__ float ws[8][128];
  int tid = threadIdx.x;
  int tx = tid & 15, ty = tid >> 4;
  int bm = blockIdx.x * 128;
  float acc[8][8];
#pragma unroll
  for (int i = 0; i < 8; ++i)
#pragma unroll
    for (int j = 0; j < 8; ++j) acc[i][j] = 0.0f;

  int lm = tid >> 1;
  int lk = (tid & 1) * 4;
  int wk = tid >> 5;
  int wn = (tid & 31) * 4;

  for (int k0 = 0; k0 < K; k0 += 8) {
    float4 a4 = *(const float4*)(A + (size_t)(bm + lm) * K + k0 + lk);
    xs[lk + 0][lm] = a4.x;
    xs[lk + 1][lm] = a4.y;
    xs[lk + 2][lm] = a4.z;
    xs[lk + 3][lm] = a4.w;
    *(float4*)&ws[wk][wn] = *(const float4*)(W + (size_t)(k0 + wk) * 128 + wn);
    __syncthreads();
#pragma unroll
    for (int k = 0; k < 8; ++k) {
      // cols split as tx*4 and 64+tx*4 -> 2-way LDS bank aliasing only (free)
      float4 xa = *(const float4*)&xs[k][ty * 8];
      float4 xb = *(const float4*)&xs[k][ty * 8 + 4];
      float4 wa = *(const float4*)&ws[k][tx * 4];
      float4 wb = *(const float4*)&ws[k][64 + tx * 4];
      float xv[8] = {xa.x, xa.y, xa.z, xa.w, xb.x, xb.y, xb.z, xb.w};
      float wv[8] = {wa.x, wa.y, wa.z, wa.w, wb.x, wb.y, wb.z, wb.w};
#pragma unroll
      for (int i = 0; i < 8; ++i)
#pragma unroll
        for (int j = 0; j < 8; ++j) acc[i][j] += xv[i] * wv[j];
    }
    __syncthreads();
  }
#pragma unroll
  for (int i = 0; i < 8; ++i) {
    size_t rb = (size_t)(bm + ty * 8 + i) * 128;
    float4 o0 = make_float4(acc[i][0], acc[i][1], acc[i][2], acc[i][3]);
    float4 o1 = make_float4(acc[i][4], acc[i][5], acc[i][6], acc[i][7]);
    *(float4*)(C + rb + tx * 4) = o0;
    *(float4*)(C + rb + 64 + tx * 4) = o1;
  }
}

// ---- CSR aggregation + bias + mish: one node per block, feature=thread ---
__global__ __launch_bounds__(128) void k_agg(const float* __restrict__ h, const int* __restrict__ rowptr,
                                             const int* __restrict__ csrc, const float* __restrict__ cw,
                                             const float* __restrict__ dinv, const float* __restrict__ bias,
                                             float* __restrict__ out) {
  int n = blockIdx.x;
  int t = threadIdx.x;
  float di = dinv[n];
  float acc = di * di * h[(size_t)n * F + t];  // self-loop
  int p0 = rowptr[n], p1 = rowptr[n + 1];
  for (int p = p0; p < p1; ++p) {
    int s = csrc[p];
    float w = cw[p];
    acc += w * h[(size_t)s * F + t];
  }
  out[(size_t)n * F + t] = mish_f(acc + bias[t]);
}

// ---- readout: o8[n,k] = mish(h[n,:]@ro_w[:,k] + ro_b[k]) -----------------
__global__ __launch_bounds__(256) void k_ro(const float* __restrict__ h, const float* __restrict__ rw,
                                            const float* __restrict__ rb, float* __restrict__ o8) {
  __shared__ float w[128 * 8];
  int t = threadIdx.x;
  for (int i = t; i < 1024; i += 256) w[i] = rw[i];
  __syncthreads();
  int n = blockIdx.x * 32 + (t >> 3);
  int k = t & 7;
  const float* hr = h + (size_t)n * F;
  float acc = rb[k];
#pragma unroll 4
  for (int j = 0; j < 128; ++j) acc += hr[j] * w[j * 8 + k];
  o8[(size_t)n * 8 + k] = mish_f(acc);
}

// ---- fc1: z[b,j] = feats[b,:]@fc1_w[:,j] + b[j]; 4 graphs per block ------
__global__ __launch_bounds__(512) void k_fc1(const float* __restrict__ feats, const float* __restrict__ w,
                                             const float* __restrict__ b, float* __restrict__ z) {
  __shared__ float fs[4][3200];
  int t = threadIdx.x;
  int bg = blockIdx.x * 4;
  for (int g = 0; g < 4; ++g)
    for (int i = t; i < 3200; i += 512) fs[g][i] = feats[(size_t)(bg + g) * 3200 + i];
  __syncthreads();
  if (t < 400) {
    float bb = b[t];
    float a0 = bb, a1 = bb, a2 = bb, a3 = bb;
    for (int k = 0; k < 3200; ++k) {
      float wv = w[(size_t)k * 400 + t];
      a0 += fs[0][k] * wv;
      a1 += fs[1][k] * wv;
      a2 += fs[2][k] * wv;
      a3 += fs[3][k] * wv;
    }
    z[(size_t)(bg + 0) * 400 + t] = a0;
    z[(size_t)(bg + 1) * 400 + t] = a1;
    z[(size_t)(bg + 2) * 400 + t] = a2;
    z[(size_t)(bg + 3) * 400 + t] = a3;
  }
}

// ---- batchnorm stats (training-mode, biased var) -> scale/shift ----------
__global__ void k_bn(const float* __restrict__ z, const float* __restrict__ gamma,
                     const float* __restrict__ beta, float* __restrict__ gs, float* __restrict__ gb) {
  int j = blockIdx.x * blockDim.x + threadIdx.x;
  if (j < 400) {
    float s = 0.f;
    for (int b = 0; b < 128; ++b) s += z[b * 400 + j];
    float mu = s * (1.0f / 128.0f);
    float v = 0.f;
    for (int b = 0; b < 128; ++b) {
      float d = z[b * 400 + j] - mu;
      v += d * d;
    }
    v *= (1.0f / 128.0f);
    float rs = rsqrtf(v + 1e-5f);
    float g = gamma[j] * rs;
    gs[j] = g;
    gb[j] = beta[j] - mu * g;
  }
}

// ---- fc2: logits[b,c] = mish(zn[b,:]) @ fc2_w[:,c] + fc2_b[c] ------------
__global__ __launch_bounds__(256) void k_fc2(const float* __restrict__ z, const float* __restrict__ gs,
                                             const float* __restrict__ gb, const float* __restrict__ w2,
                                             const float* __restrict__ b2, float* __restrict__ out) {
  int t = threadIdx.x;
  int bg = t >> 1, c = t & 1;
  float acc = b2[c];
  for (int j = 0; j < 400; ++j) {
    float zn = z[bg * 400 + j] * gs[j] + gb[j];
    acc += mish_f(zn) * w2[j * 2 + c];
  }
  out[bg * 2 + c] = acc;
}

extern "C" void kernel_launch(void* const* d_in, const int* in_sizes, int n_in,
                              void* d_out, int out_size, void* d_ws, size_t ws_size,
                              hipStream_t stream) {
  (void)in_sizes; (void)n_in; (void)out_size; (void)ws_size;
  const float* x   = (const float*)d_in[0];
  const int*   ei  = (const int*)d_in[1];
  const float* ew  = (const float*)d_in[2];
  const float* c1w = (const float*)d_in[4];
  const float* c1b = (const float*)d_in[5];
  const float* c2w = (const float*)d_in[6];
  const float* c2b = (const float*)d_in[7];
  const float* rw  = (const float*)d_in[8];
  const float* rb  = (const float*)d_in[9];
  const float* f1w = (const float*)d_in[10];
  const float* f1b = (const float*)d_in[11];
  const float* bng = (const float*)d_in[12];
  const float* bnb = (const float*)d_in[13];
  const float* f2w = (const float*)d_in[14];
  const float* f2b = (const float*)d_in[15];
  float* out = (float*)d_out;

  char* ws = (char*)d_ws;
  size_t off = 0;
  auto alloc = [&](size_t bytes) {
    void* p = ws + off;
    off = (off + bytes + 255) & ~(size_t)255;
    return p;
  };
  float* deg    = (float*)alloc((size_t)NN * 4);  // becomes dinv in-place
  int*   cnt    = (int*)alloc((size_t)NN * 4);
  int*   rowptr = (int*)alloc((size_t)(NN + 1) * 4);
  int*   cursor = (int*)alloc((size_t)NN * 4);
  int*   bsum   = (int*)alloc(200 * 4);
  int*   boff   = (int*)alloc(200 * 4);
  int*   csrc   = (int*)alloc((size_t)NE * 4);
  float* cw     = (float*)alloc((size_t)NE * 4);
  float* bufA   = (float*)alloc((size_t)NN * F * 4);  // h (pre-agg)
  float* bufB   = (float*)alloc((size_t)NN * F * 4);  // h (post-agg+mish)
  float* o8     = (float*)alloc((size_t)NN * 8 * 4);
  float* z      = (float*)alloc((size_t)128 * 400 * 4);
  float* gs     = (float*)alloc(400 * 4);
  float* gb     = (float*)alloc(400 * 4);

  hipMemsetAsync(deg, 0, (size_t)NN * 4, stream);
  hipMemsetAsync(cnt, 0, (size_t)NN * 4, stream);

  k_edge_deg<<<(NE + 255) / 256, 256, 0, stream>>>(ei, ew, deg, cnt);
  k_dinv<<<(NN + 255) / 256, 256, 0, stream>>>(deg);
  k_scan1<<<NN / 256, 256, 0, stream>>>(cnt, bsum);
  k_scan2<<<1, 256, 0, stream>>>(bsum, boff, rowptr);
  k_scan3<<<NN / 256, 256, 0, stream>>>(cnt, boff, rowptr, cursor);
  k_fill<<<(NE + 255) / 256, 256, 0, stream>>>(ei, ew, deg, cursor, csrc, cw);

  // conv1: h = x@W1 ; agg+bias+mish
  k_gemm<<<NN / 128, 256, 0, stream>>>(x, c1w, bufA, NN, 400);
  k_agg<<<NN, 128, 0, stream>>>(bufA, rowptr, csrc, cw, deg, c1b, bufB);
  // conv2
  k_gemm<<<NN / 128, 256, 0, stream>>>(bufB, c2w, bufA, NN, 128);
  k_agg<<<NN, 128, 0, stream>>>(bufA, rowptr, csrc, cw, deg, c2b, bufB);
  // readout -> feats (o8 flat IS feats[128][3200])
  k_ro<<<NN / 32, 256, 0, stream>>>(bufB, rw, rb, o8);
  k_fc1<<<32, 512, 0, stream>>>(o8, f1w, f1b, z);
  k_bn<<<2, 256, 0, stream>>>(z, bng, bnb, gs, gb);
  k_fc2<<<1, 256, 0, stream>>>(z, gs, gb, f2w, f2b, out);
}

// Round 2
// 1120.401 us; speedup vs baseline: 1.1681x; 1.1681x over previous
//
#include <hip/hip_runtime.h>
#include <math.h>

#define NN 51200
#define NE 2048000
#define F 128

__device__ __forceinline__ float mish_f(float x) {
  if (x > 20.0f) return x;
  float e = __expf(x);
  float w = 1.0f + e;
  w = w * w;
  return x * (w - 1.0f) / (w + 1.0f);
}

// ---- degree + in-degree count -------------------------------------------
__global__ void k_edge_deg(const int* __restrict__ ei, const float* __restrict__ ew,
                           float* __restrict__ deg, int* __restrict__ cnt) {
  int e = blockIdx.x * blockDim.x + threadIdx.x;
  if (e < NE) {
    int c = ei[NE + e];
    atomicAdd(&deg[c], ew[e]);
    atomicAdd(&cnt[c], 1);
  }
}

__global__ void k_dinv(float* __restrict__ deg) {
  int i = blockIdx.x * blockDim.x + threadIdx.x;
  if (i < NN) deg[i] = rsqrtf(deg[i] + 1.0f);  // +1 = self-loop weight
}

// ---- hierarchical exclusive scan of cnt -> rowptr, cursor ----------------
__global__ __launch_bounds__(256) void k_scan1(const int* __restrict__ cnt, int* __restrict__ bsum) {
  int i = blockIdx.x * 256 + threadIdx.x;
  int s = cnt[i];
#pragma unroll
  for (int off = 1; off < 64; off <<= 1) s += __shfl_xor(s, off);
  __shared__ int wsum[4];
  if ((threadIdx.x & 63) == 0) wsum[threadIdx.x >> 6] = s;
  __syncthreads();
  if (threadIdx.x == 0) bsum[blockIdx.x] = wsum[0] + wsum[1] + wsum[2] + wsum[3];
}

__global__ __launch_bounds__(256) void k_scan2(const int* __restrict__ bsum, int* __restrict__ boff,
                                               int* __restrict__ rowptr) {
  int t = threadIdx.x;
  int lane = t & 63, wid = t >> 6;
  int v = (t < 200) ? bsum[t] : 0;
  int x = v;
#pragma unroll
  for (int off = 1; off < 64; off <<= 1) {
    int y = __shfl_up(x, off);
    if (lane >= off) x += y;
  }
  __shared__ int ws4[4];
  if (lane == 63) ws4[wid] = x;
  __syncthreads();
  int woff = 0;
  for (int k = 0; k < wid; ++k) woff += ws4[k];
  if (t < 200) boff[t] = woff + x - v;
  if (t == 255) rowptr[NN] = woff + x;  // grand total
}

__global__ __launch_bounds__(256) void k_scan3(const int* __restrict__ cnt, const int* __restrict__ boff,
                                               int* __restrict__ rowptr, int* __restrict__ cursor) {
  int i = blockIdx.x * 256 + threadIdx.x;
  int t = threadIdx.x;
  int lane = t & 63, wid = t >> 6;
  int v = cnt[i];
  int x = v;
#pragma unroll
  for (int off = 1; off < 64; off <<= 1) {
    int y = __shfl_up(x, off);
    if (lane >= off) x += y;
  }
  __shared__ int ws4[4];
  if (lane == 63) ws4[wid] = x;
  __syncthreads();
  int woff = boff[blockIdx.x];
  for (int k = 0; k < wid; ++k) woff += ws4[k];
  int excl = woff + x - v;
  rowptr[i] = excl;
  cursor[i] = excl;
}

// ---- CSR fill: edge -> (src,norm) bucketed by dst ------------------------
__global__ void k_fill(const int* __restrict__ ei, const float* __restrict__ ew,
                       const float* __restrict__ dinv, int* __restrict__ cursor,
                       int* __restrict__ csrc, float* __restrict__ cw) {
  int e = blockIdx.x * blockDim.x + threadIdx.x;
  if (e < NE) {
    int r = ei[e], c = ei[NE + e];
    int p = atomicAdd(&cursor[c], 1);
    csrc[p] = r;
    cw[p] = dinv[r] * ew[e] * dinv[c];
  }
}

// ---- fp32 GEMM: C[M,128] = A[M,K] @ W[K,128], 128x128 tile, 8x8/thread ---
__global__ __launch_bounds__(256) void k_gemm(const float* __restrict__ A, const float* __restrict__ W,
                                              float* __restrict__ C, int M, int K) {
  __shared__ float xs[8][128];  // transposed A tile: xs[k][m]
  __shared__ float ws[8][128];
  int tid = threadIdx.x;
  int tx = tid & 15, ty = tid >> 4;
  int bm = blockIdx.x * 128;
  float acc[8][8];
#pragma unroll
  for (int i = 0; i < 8; ++i)
#pragma unroll
    for (int j = 0; j < 8; ++j) acc[i][j] = 0.0f;

  int lm = tid >> 1;
  int lk = (tid & 1) * 4;
  int wk = tid >> 5;
  int wn = (tid & 31) * 4;

  for (int k0 = 0; k0 < K; k0 += 8) {
    float4 a4 = *(const float4*)(A + (size_t)(bm + lm) * K + k0 + lk);
    xs[lk + 0][lm] = a4.x;
    xs[lk + 1][lm] = a4.y;
    xs[lk + 2][lm] = a4.z;
    xs[lk + 3][lm] = a4.w;
    *(float4*)&ws[wk][wn] = *(const float4*)(W + (size_t)(k0 + wk) * 128 + wn);
    __syncthreads();
#pragma unroll
    for (int k = 0; k < 8; ++k) {
      float4 xa = *(const float4*)&xs[k][ty * 8];
      float4 xb = *(const float4*)&xs[k][ty * 8 + 4];
      float4 wa = *(const float4*)&ws[k][tx * 4];
      float4 wb = *(const float4*)&ws[k][64 + tx * 4];
      float xv[8] = {xa.x, xa.y, xa.z, xa.w, xb.x, xb.y, xb.z, xb.w};
      float wv[8] = {wa.x, wa.y, wa.z, wa.w, wb.x, wb.y, wb.z, wb.w};
#pragma unroll
      for (int i = 0; i < 8; ++i)
#pragma unroll
        for (int j = 0; j < 8; ++j) acc[i][j] += xv[i] * wv[j];
    }
    __syncthreads();
  }
#pragma unroll
  for (int i = 0; i < 8; ++i) {
    size_t rb = (size_t)(bm + ty * 8 + i) * 128;
    float4 o0 = make_float4(acc[i][0], acc[i][1], acc[i][2], acc[i][3]);
    float4 o1 = make_float4(acc[i][4], acc[i][5], acc[i][6], acc[i][7]);
    *(float4*)(C + rb + tx * 4) = o0;
    *(float4*)(C + rb + 64 + tx * 4) = o1;
  }
}

// ---- CSR aggregation + bias + mish: one node per block, feature=thread ---
__global__ __launch_bounds__(128) void k_agg(const float* __restrict__ h, const int* __restrict__ rowptr,
                                             const int* __restrict__ csrc, const float* __restrict__ cw,
                                             const float* __restrict__ dinv, const float* __restrict__ bias,
                                             float* __restrict__ out) {
  int n = blockIdx.x;
  int t = threadIdx.x;
  float di = dinv[n];
  float acc = di * di * h[(size_t)n * F + t];  // self-loop
  int p0 = rowptr[n], p1 = rowptr[n + 1];
  for (int p = p0; p < p1; ++p) {
    int s = csrc[p];
    float w = cw[p];
    acc += w * h[(size_t)s * F + t];
  }
  out[(size_t)n * F + t] = mish_f(acc + bias[t]);
}

// ---- readout: o8[n,k] = mish(h[n,:]@ro_w[:,k] + ro_b[k]) -----------------
__global__ __launch_bounds__(256) void k_ro(const float* __restrict__ h, const float* __restrict__ rw,
                                            const float* __restrict__ rb, float* __restrict__ o8) {
  __shared__ float w[128 * 8];
  int t = threadIdx.x;
  for (int i = t; i < 1024; i += 256) w[i] = rw[i];
  __syncthreads();
  int n = blockIdx.x * 32 + (t >> 3);
  int k = t & 7;
  const float* hr = h + (size_t)n * F;
  float acc = rb[k];
#pragma unroll 4
  for (int j = 0; j < 128; ++j) acc += hr[j] * w[j * 8 + k];
  o8[(size_t)n * 8 + k] = mish_f(acc);
}

// ---- fc1 split-K: z += feats[g, kc:kc+128] @ w[kc:kc+128, :] -------------
// z pre-initialized with bias by k_fc1_init. Grid: (25 K-chunks, 16 graph-groups)
__global__ void k_fc1_init(const float* __restrict__ b, float* __restrict__ z) {
  int i = blockIdx.x * blockDim.x + threadIdx.x;
  if (i < 128 * 400) z[i] = b[i % 400];
}

__global__ __launch_bounds__(448) void k_fc1(const float* __restrict__ feats, const float* __restrict__ w,
                                             float* __restrict__ z) {
  __shared__ float fs[8][128];
  int t = threadIdx.x;
  int kc = blockIdx.x * 128;        // K-chunk base (25 chunks of 128 = 3200)
  int g0 = blockIdx.y * 8;          // graph-group base (16 groups of 8 = 128)
  for (int i = t; i < 1024; i += 448) {
    int g = i >> 7, k = i & 127;
    fs[g][k] = feats[(size_t)(g0 + g) * 3200 + kc + k];
  }
  __syncthreads();
  if (t < 400) {
    float a[8];
#pragma unroll
    for (int g = 0; g < 8; ++g) a[g] = 0.0f;
    for (int k = 0; k < 128; ++k) {
      float wv = w[(size_t)(kc + k) * 400 + t];
#pragma unroll
      for (int g = 0; g < 8; ++g) a[g] += fs[g][k] * wv;
    }
#pragma unroll
    for (int g = 0; g < 8; ++g) atomicAdd(&z[(size_t)(g0 + g) * 400 + t], a[g]);
  }
}

// ---- batchnorm stats (training-mode, biased var) -> scale/shift ----------
__global__ void k_bn(const float* __restrict__ z, const float* __restrict__ gamma,
                     const float* __restrict__ beta, float* __restrict__ gs, float* __restrict__ gb) {
  int j = blockIdx.x * blockDim.x + threadIdx.x;
  if (j < 400) {
    float s = 0.f;
    for (int b = 0; b < 128; ++b) s += z[b * 400 + j];
    float mu = s * (1.0f / 128.0f);
    float v = 0.f;
    for (int b = 0; b < 128; ++b) {
      float d = z[b * 400 + j] - mu;
      v += d * d;
    }
    v *= (1.0f / 128.0f);
    float rs = rsqrtf(v + 1e-5f);
    float g = gamma[j] * rs;
    gs[j] = g;
    gb[j] = beta[j] - mu * g;
  }
}

// ---- fc2: logits[b,c] = mish(zn[b,:]) @ fc2_w[:,c] + fc2_b[c] ------------
__global__ __launch_bounds__(256) void k_fc2(const float* __restrict__ z, const float* __restrict__ gs,
                                             const float* __restrict__ gb, const float* __restrict__ w2,
                                             const float* __restrict__ b2, float* __restrict__ out) {
  int t = threadIdx.x;
  int bg = t >> 1, c = t & 1;
  float acc = b2[c];
  for (int j = 0; j < 400; ++j) {
    float zn = z[bg * 400 + j] * gs[j] + gb[j];
    acc += mish_f(zn) * w2[j * 2 + c];
  }
  out[bg * 2 + c] = acc;
}

extern "C" void kernel_launch(void* const* d_in, const int* in_sizes, int n_in,
                              void* d_out, int out_size, void* d_ws, size_t ws_size,
                              hipStream_t stream) {
  (void)in_sizes; (void)n_in; (void)out_size; (void)ws_size;
  const float* x   = (const float*)d_in[0];
  const int*   ei  = (const int*)d_in[1];
  const float* ew  = (const float*)d_in[2];
  const float* c1w = (const float*)d_in[4];
  const float* c1b = (const float*)d_in[5];
  const float* c2w = (const float*)d_in[6];
  const float* c2b = (const float*)d_in[7];
  const float* rw  = (const float*)d_in[8];
  const float* rb  = (const float*)d_in[9];
  const float* f1w = (const float*)d_in[10];
  const float* f1b = (const float*)d_in[11];
  const float* bng = (const float*)d_in[12];
  const float* bnb = (const float*)d_in[13];
  const float* f2w = (const float*)d_in[14];
  const float* f2b = (const float*)d_in[15];
  float* out = (float*)d_out;

  char* ws = (char*)d_ws;
  size_t off = 0;
  auto alloc = [&](size_t bytes) {
    void* p = ws + off;
    off = (off + bytes + 255) & ~(size_t)255;
    return p;
  };
  float* deg    = (float*)alloc((size_t)NN * 4);  // becomes dinv in-place
  int*   cnt    = (int*)alloc((size_t)NN * 4);
  int*   rowptr = (int*)alloc((size_t)(NN + 1) * 4);
  int*   cursor = (int*)alloc((size_t)NN * 4);
  int*   bsum   = (int*)alloc(200 * 4);
  int*   boff   = (int*)alloc(200 * 4);
  int*   csrc   = (int*)alloc((size_t)NE * 4);
  float* cw     = (float*)alloc((size_t)NE * 4);
  float* bufA   = (float*)alloc((size_t)NN * F * 4);  // h (pre-agg)
  float* bufB   = (float*)alloc((size_t)NN * F * 4);  // h (post-agg+mish)
  float* o8     = (float*)alloc((size_t)NN * 8 * 4);
  float* z      = (float*)alloc((size_t)128 * 400 * 4);
  float* gs     = (float*)alloc(400 * 4);
  float* gb     = (float*)alloc(400 * 4);

  hipMemsetAsync(deg, 0, (size_t)NN * 4, stream);
  hipMemsetAsync(cnt, 0, (size_t)NN * 4, stream);

  k_edge_deg<<<(NE + 255) / 256, 256, 0, stream>>>(ei, ew, deg, cnt);
  k_dinv<<<(NN + 255) / 256, 256, 0, stream>>>(deg);
  k_scan1<<<NN / 256, 256, 0, stream>>>(cnt, bsum);
  k_scan2<<<1, 256, 0, stream>>>(bsum, boff, rowptr);
  k_scan3<<<NN / 256, 256, 0, stream>>>(cnt, boff, rowptr, cursor);
  k_fill<<<(NE + 255) / 256, 256, 0, stream>>>(ei, ew, deg, cursor, csrc, cw);

  // conv1: h = x@W1 ; agg+bias+mish
  k_gemm<<<NN / 128, 256, 0, stream>>>(x, c1w, bufA, NN, 400);
  k_agg<<<NN, 128, 0, stream>>>(bufA, rowptr, csrc, cw, deg, c1b, bufB);
  // conv2
  k_gemm<<<NN / 128, 256, 0, stream>>>(bufB, c2w, bufA, NN, 128);
  k_agg<<<NN, 128, 0, stream>>>(bufA, rowptr, csrc, cw, deg, c2b, bufB);
  // readout -> feats (o8 flat IS feats[128][3200])
  k_ro<<<NN / 32, 256, 0, stream>>>(bufB, rw, rb, o8);
  k_fc1_init<<<(128 * 400 + 255) / 256, 256, 0, stream>>>(f1b, z);
  {
    dim3 g(25, 16);
    k_fc1<<<g, 448, 0, stream>>>(o8, f1w, z);
  }
  k_bn<<<2, 256, 0, stream>>>(z, bng, bnb, gs, gb);
  k_fc2<<<1, 256, 0, stream>>>(z, gs, gb, f2w, f2b, out);
}

// Round 3
// 903.473 us; speedup vs baseline: 1.4485x; 1.2401x over previous
//
#include <hip/hip_runtime.h>
#include <hip/hip_fp16.h>
#include <math.h>

#define NN 51200
#define NE 2048000
#define F 128

__device__ __forceinline__ float mish_f(float x) {
  if (x > 20.0f) return x;
  float e = __expf(x);
  float w = 1.0f + e;
  w = w * w;
  return x * (w - 1.0f) / (w + 1.0f);
}

// ---- degree + in-degree count -------------------------------------------
__global__ void k_edge_deg(const int* __restrict__ ei, const float* __restrict__ ew,
                           float* __restrict__ deg, int* __restrict__ cnt) {
  int e = blockIdx.x * blockDim.x + threadIdx.x;
  if (e < NE) {
    int c = ei[NE + e];
    atomicAdd(&deg[c], ew[e]);
    atomicAdd(&cnt[c], 1);
  }
}

__global__ void k_dinv(float* __restrict__ deg) {
  int i = blockIdx.x * blockDim.x + threadIdx.x;
  if (i < NN) deg[i] = rsqrtf(deg[i] + 1.0f);  // +1 = self-loop weight
}

// ---- hierarchical exclusive scan of cnt -> rowptr, cursor ----------------
__global__ __launch_bounds__(256) void k_scan1(const int* __restrict__ cnt, int* __restrict__ bsum) {
  int i = blockIdx.x * 256 + threadIdx.x;
  int s = cnt[i];
#pragma unroll
  for (int off = 1; off < 64; off <<= 1) s += __shfl_xor(s, off);
  __shared__ int wsum[4];
  if ((threadIdx.x & 63) == 0) wsum[threadIdx.x >> 6] = s;
  __syncthreads();
  if (threadIdx.x == 0) bsum[blockIdx.x] = wsum[0] + wsum[1] + wsum[2] + wsum[3];
}

__global__ __launch_bounds__(256) void k_scan2(const int* __restrict__ bsum, int* __restrict__ boff,
                                               int* __restrict__ rowptr) {
  int t = threadIdx.x;
  int lane = t & 63, wid = t >> 6;
  int v = (t < 200) ? bsum[t] : 0;
  int x = v;
#pragma unroll
  for (int off = 1; off < 64; off <<= 1) {
    int y = __shfl_up(x, off);
    if (lane >= off) x += y;
  }
  __shared__ int ws4[4];
  if (lane == 63) ws4[wid] = x;
  __syncthreads();
  int woff = 0;
  for (int k = 0; k < wid; ++k) woff += ws4[k];
  if (t < 200) boff[t] = woff + x - v;
  if (t == 255) rowptr[NN] = woff + x;  // grand total
}

__global__ __launch_bounds__(256) void k_scan3(const int* __restrict__ cnt, const int* __restrict__ boff,
                                               int* __restrict__ rowptr, int* __restrict__ cursor) {
  int i = blockIdx.x * 256 + threadIdx.x;
  int t = threadIdx.x;
  int lane = t & 63, wid = t >> 6;
  int v = cnt[i];
  int x = v;
#pragma unroll
  for (int off = 1; off < 64; off <<= 1) {
    int y = __shfl_up(x, off);
    if (lane >= off) x += y;
  }
  __shared__ int ws4[4];
  if (lane == 63) ws4[wid] = x;
  __syncthreads();
  int woff = boff[blockIdx.x];
  for (int k = 0; k < wid; ++k) woff += ws4[k];
  int excl = woff + x - v;
  rowptr[i] = excl;
  cursor[i] = excl;
}

// ---- CSR fill: edge -> packed (src, norm-bits) bucketed by dst -----------
__global__ void k_fill(const int* __restrict__ ei, const float* __restrict__ ew,
                       const float* __restrict__ dinv, int* __restrict__ cursor,
                       int2* __restrict__ csr) {
  int e = blockIdx.x * blockDim.x + threadIdx.x;
  if (e < NE) {
    int r = ei[e], c = ei[NE + e];
    int p = atomicAdd(&cursor[c], 1);
    float nw = dinv[r] * ew[e] * dinv[c];
    csr[p] = make_int2(r, __float_as_int(nw));
  }
}

// ---- fp32 GEMM: C[M,128](fp16) = A[M,K] @ W[K,128], 128x128 tile ---------
__global__ __launch_bounds__(256) void k_gemm(const float* __restrict__ A, const float* __restrict__ W,
                                              __half* __restrict__ C, int M, int K) {
  __shared__ float xs[8][128];  // transposed A tile: xs[k][m]
  __shared__ float ws[8][128];
  int tid = threadIdx.x;
  int tx = tid & 15, ty = tid >> 4;
  int bm = blockIdx.x * 128;
  float acc[8][8];
#pragma unroll
  for (int i = 0; i < 8; ++i)
#pragma unroll
    for (int j = 0; j < 8; ++j) acc[i][j] = 0.0f;

  int lm = tid >> 1;
  int lk = (tid & 1) * 4;
  int wk = tid >> 5;
  int wn = (tid & 31) * 4;

  for (int k0 = 0; k0 < K; k0 += 8) {
    float4 a4 = *(const float4*)(A + (size_t)(bm + lm) * K + k0 + lk);
    xs[lk + 0][lm] = a4.x;
    xs[lk + 1][lm] = a4.y;
    xs[lk + 2][lm] = a4.z;
    xs[lk + 3][lm] = a4.w;
    *(float4*)&ws[wk][wn] = *(const float4*)(W + (size_t)(k0 + wk) * 128 + wn);
    __syncthreads();
#pragma unroll
    for (int k = 0; k < 8; ++k) {
      float4 xa = *(const float4*)&xs[k][ty * 8];
      float4 xb = *(const float4*)&xs[k][ty * 8 + 4];
      float4 wa = *(const float4*)&ws[k][tx * 4];
      float4 wb = *(const float4*)&ws[k][64 + tx * 4];
      float xv[8] = {xa.x, xa.y, xa.z, xa.w, xb.x, xb.y, xb.z, xb.w};
      float wv[8] = {wa.x, wa.y, wa.z, wa.w, wb.x, wb.y, wb.z, wb.w};
#pragma unroll
      for (int i = 0; i < 8; ++i)
#pragma unroll
        for (int j = 0; j < 8; ++j) acc[i][j] += xv[i] * wv[j];
    }
    __syncthreads();
  }
#pragma unroll
  for (int i = 0; i < 8; ++i) {
    size_t rb = (size_t)(bm + ty * 8 + i) * 128;
    __half2 p0 = __floats2half2_rn(acc[i][0], acc[i][1]);
    __half2 p1 = __floats2half2_rn(acc[i][2], acc[i][3]);
    __half2 p2 = __floats2half2_rn(acc[i][4], acc[i][5]);
    __half2 p3 = __floats2half2_rn(acc[i][6], acc[i][7]);
    union { __half2 h[2]; uint2 u; } u0 = {{p0, p1}}, u1 = {{p2, p3}};
    *(uint2*)(C + rb + tx * 4) = u0.u;
    *(uint2*)(C + rb + 64 + tx * 4) = u1.u;
  }
}

// ---- CSR aggregation + bias + mish: one node per WAVE, half2 gathers -----
__global__ __launch_bounds__(256) void k_agg(const __half2* __restrict__ h, const int* __restrict__ rowptr,
                                             const int2* __restrict__ csr, const float* __restrict__ dinv,
                                             const float* __restrict__ bias, float* __restrict__ out) {
  int lane = threadIdx.x & 63;
  int n = blockIdx.x * 4 + (threadIdx.x >> 6);
  float di = dinv[n];
  float2 self = __half22float2(h[(size_t)n * 64 + lane]);
  float2 acc;
  acc.x = di * di * self.x;
  acc.y = di * di * self.y;
  int p0 = rowptr[n], p1 = rowptr[n + 1];
  int p = p0;
  for (; p + 1 < p1; p += 2) {
    int2 c0 = csr[p];
    int2 c1 = csr[p + 1];
    float2 f0 = __half22float2(h[(size_t)c0.x * 64 + lane]);
    float2 f1 = __half22float2(h[(size_t)c1.x * 64 + lane]);
    float w0 = __int_as_float(c0.y), w1 = __int_as_float(c1.y);
    acc.x += w0 * f0.x + w1 * f1.x;
    acc.y += w0 * f0.y + w1 * f1.y;
  }
  if (p < p1) {
    int2 c0 = csr[p];
    float2 f0 = __half22float2(h[(size_t)c0.x * 64 + lane]);
    float w0 = __int_as_float(c0.y);
    acc.x += w0 * f0.x;
    acc.y += w0 * f0.y;
  }
  float2 bb = *((const float2*)bias + lane);
  float2 o;
  o.x = mish_f(acc.x + bb.x);
  o.y = mish_f(acc.y + bb.y);
  *((float2*)out + (size_t)n * 64 + lane) = o;
}

// ---- readout: o8[n,k] = mish(h[n,:]@ro_w[:,k] + ro_b[k]) -----------------
__global__ __launch_bounds__(256) void k_ro(const float* __restrict__ h, const float* __restrict__ rw,
                                            const float* __restrict__ rb, float* __restrict__ o8) {
  __shared__ float w[128 * 8];
  int t = threadIdx.x;
  for (int i = t; i < 1024; i += 256) w[i] = rw[i];
  __syncthreads();
  int n = blockIdx.x * 32 + (t >> 3);
  int k = t & 7;
  const float* hr = h + (size_t)n * F;
  float acc = rb[k];
#pragma unroll 4
  for (int j = 0; j < 128; ++j) acc += hr[j] * w[j * 8 + k];
  o8[(size_t)n * 8 + k] = mish_f(acc);
}

// ---- fc1 split-K: z += feats[g, kc:kc+128] @ w[kc:kc+128, :] -------------
__global__ void k_fc1_init(const float* __restrict__ b, float* __restrict__ z) {
  int i = blockIdx.x * blockDim.x + threadIdx.x;
  if (i < 128 * 400) z[i] = b[i % 400];
}

__global__ __launch_bounds__(448) void k_fc1(const float* __restrict__ feats, const float* __restrict__ w,
                                             float* __restrict__ z) {
  __shared__ float fs[8][128];
  int t = threadIdx.x;
  int kc = blockIdx.x * 128;        // 25 chunks of 128 = 3200
  int g0 = blockIdx.y * 8;          // 16 groups of 8 = 128 graphs
  for (int i = t; i < 1024; i += 448) {
    int g = i >> 7, k = i & 127;
    fs[g][k] = feats[(size_t)(g0 + g) * 3200 + kc + k];
  }
  __syncthreads();
  if (t < 400) {
    float a[8];
#pragma unroll
    for (int g = 0; g < 8; ++g) a[g] = 0.0f;
    for (int k = 0; k < 128; ++k) {
      float wv = w[(size_t)(kc + k) * 400 + t];
#pragma unroll
      for (int g = 0; g < 8; ++g) a[g] += fs[g][k] * wv;
    }
#pragma unroll
    for (int g = 0; g < 8; ++g) atomicAdd(&z[(size_t)(g0 + g) * 400 + t], a[g]);
  }
}

// ---- batchnorm stats (training-mode, biased var) -> scale/shift ----------
__global__ void k_bn(const float* __restrict__ z, const float* __restrict__ gamma,
                     const float* __restrict__ beta, float* __restrict__ gs, float* __restrict__ gb) {
  int j = blockIdx.x * blockDim.x + threadIdx.x;
  if (j < 400) {
    float s = 0.f;
    for (int b = 0; b < 128; ++b) s += z[b * 400 + j];
    float mu = s * (1.0f / 128.0f);
    float v = 0.f;
    for (int b = 0; b < 128; ++b) {
      float d = z[b * 400 + j] - mu;
      v += d * d;
    }
    v *= (1.0f / 128.0f);
    float rs = rsqrtf(v + 1e-5f);
    float g = gamma[j] * rs;
    gs[j] = g;
    gb[j] = beta[j] - mu * g;
  }
}

// ---- fc2: logits[b,c] = mish(zn[b,:]) @ fc2_w[:,c] + fc2_b[c] ------------
__global__ __launch_bounds__(256) void k_fc2(const float* __restrict__ z, const float* __restrict__ gs,
                                             const float* __restrict__ gb, const float* __restrict__ w2,
                                             const float* __restrict__ b2, float* __restrict__ out) {
  int t = threadIdx.x;
  int bg = t >> 1, c = t & 1;
  float acc = b2[c];
  for (int j = 0; j < 400; ++j) {
    float zn = z[bg * 400 + j] * gs[j] + gb[j];
    acc += mish_f(zn) * w2[j * 2 + c];
  }
  out[bg * 2 + c] = acc;
}

extern "C" void kernel_launch(void* const* d_in, const int* in_sizes, int n_in,
                              void* d_out, int out_size, void* d_ws, size_t ws_size,
                              hipStream_t stream) {
  (void)in_sizes; (void)n_in; (void)out_size; (void)ws_size;
  const float* x   = (const float*)d_in[0];
  const int*   ei  = (const int*)d_in[1];
  const float* ew  = (const float*)d_in[2];
  const float* c1w = (const float*)d_in[4];
  const float* c1b = (const float*)d_in[5];
  const float* c2w = (const float*)d_in[6];
  const float* c2b = (const float*)d_in[7];
  const float* rw  = (const float*)d_in[8];
  const float* rb  = (const float*)d_in[9];
  const float* f1w = (const float*)d_in[10];
  const float* f1b = (const float*)d_in[11];
  const float* bng = (const float*)d_in[12];
  const float* bnb = (const float*)d_in[13];
  const float* f2w = (const float*)d_in[14];
  const float* f2b = (const float*)d_in[15];
  float* out = (float*)d_out;

  char* ws = (char*)d_ws;
  size_t off = 0;
  auto alloc = [&](size_t bytes) {
    void* p = ws + off;
    off = (off + bytes + 255) & ~(size_t)255;
    return p;
  };
  float* deg    = (float*)alloc((size_t)NN * 4);  // becomes dinv in-place
  int*   cnt    = (int*)alloc((size_t)NN * 4);
  int*   rowptr = (int*)alloc((size_t)(NN + 1) * 4);
  int*   cursor = (int*)alloc((size_t)NN * 4);
  int*   bsum   = (int*)alloc(200 * 4);
  int*   boff   = (int*)alloc(200 * 4);
  int2*  csr    = (int2*)alloc((size_t)NE * 8);
  __half* bufA  = (__half*)alloc((size_t)NN * F * 2);  // h pre-agg (fp16)
  float* bufB   = (float*)alloc((size_t)NN * F * 4);   // h post-agg+mish
  float* o8     = (float*)alloc((size_t)NN * 8 * 4);
  float* z      = (float*)alloc((size_t)128 * 400 * 4);
  float* gs     = (float*)alloc(400 * 4);
  float* gb     = (float*)alloc(400 * 4);

  hipMemsetAsync(deg, 0, (size_t)NN * 4, stream);
  hipMemsetAsync(cnt, 0, (size_t)NN * 4, stream);

  k_edge_deg<<<(NE + 255) / 256, 256, 0, stream>>>(ei, ew, deg, cnt);
  k_dinv<<<(NN + 255) / 256, 256, 0, stream>>>(deg);
  k_scan1<<<NN / 256, 256, 0, stream>>>(cnt, bsum);
  k_scan2<<<1, 256, 0, stream>>>(bsum, boff, rowptr);
  k_scan3<<<NN / 256, 256, 0, stream>>>(cnt, boff, rowptr, cursor);
  k_fill<<<(NE + 255) / 256, 256, 0, stream>>>(ei, ew, deg, cursor, csr);

  // conv1: h = x@W1 (fp16 out) ; agg+bias+mish (fp32 out)
  k_gemm<<<NN / 128, 256, 0, stream>>>(x, c1w, bufA, NN, 400);
  k_agg<<<NN / 4, 256, 0, stream>>>((const __half2*)bufA, rowptr, csr, deg, c1b, bufB);
  // conv2
  k_gemm<<<NN / 128, 256, 0, stream>>>(bufB, c2w, bufA, NN, 128);
  k_agg<<<NN / 4, 256, 0, stream>>>((const __half2*)bufA, rowptr, csr, deg, c2b, bufB);
  // readout -> feats (o8 flat IS feats[128][3200])
  k_ro<<<NN / 32, 256, 0, stream>>>(bufB, rw, rb, o8);
  k_fc1_init<<<(128 * 400 + 255) / 256, 256, 0, stream>>>(f1b, z);
  {
    dim3 g(25, 16);
    k_fc1<<<g, 448, 0, stream>>>(o8, f1w, z);
  }
  k_bn<<<2, 256, 0, stream>>>(z, bng, bnb, gs, gb);
  k_fc2<<<1, 256, 0, stream>>>(z, gs, gb, f2w, f2b, out);
}

// Round 4
// 781.405 us; speedup vs baseline: 1.6748x; 1.1562x over previous
//
#include <hip/hip_runtime.h>
#include <hip/hip_fp16.h>
#include <math.h>

#define NN 51200
#define NE 2048000
#define F 128

__device__ __forceinline__ float mish_f(float x) {
  if (x > 20.0f) return x;
  float e = __expf(x);
  float w = 1.0f + e;
  w = w * w;
  return x * (w - 1.0f) / (w + 1.0f);
}

// ---- single packed atomic per edge: hi24=count, lo40=fixed-point ew sum --
// Returned old value's hi bits = this edge's rank among same-dst edges.
__global__ void k_edge_cnt(const int* __restrict__ ei, const float* __restrict__ ew,
                           unsigned long long* __restrict__ acc, int* __restrict__ rank) {
  int e = blockIdx.x * blockDim.x + threadIdx.x;
  if (e < NE) {
    int c = ei[NE + e];
    unsigned long long fx = (unsigned long long)(unsigned)(ew[e] * 16777216.0f + 0.5f);
    unsigned long long old = atomicAdd(&acc[c], (1ULL << 40) | fx);
    rank[e] = (int)(old >> 40);
  }
}

// ---- unpack: dinv = rsqrt(deg+1), cnt for scan ---------------------------
__global__ void k_dinv(const unsigned long long* __restrict__ acc, float* __restrict__ dinv,
                       int* __restrict__ cnt) {
  int i = blockIdx.x * blockDim.x + threadIdx.x;
  if (i < NN) {
    unsigned long long v = acc[i];
    cnt[i] = (int)(v >> 40);
    double deg = (double)(v & ((1ULL << 40) - 1)) * (1.0 / 16777216.0);
    dinv[i] = rsqrtf((float)deg + 1.0f);  // +1 = self-loop weight
  }
}

// ---- hierarchical exclusive scan of cnt -> rowptr ------------------------
__global__ __launch_bounds__(256) void k_scan1(const int* __restrict__ cnt, int* __restrict__ bsum) {
  int i = blockIdx.x * 256 + threadIdx.x;
  int s = cnt[i];
#pragma unroll
  for (int off = 1; off < 64; off <<= 1) s += __shfl_xor(s, off);
  __shared__ int wsum[4];
  if ((threadIdx.x & 63) == 0) wsum[threadIdx.x >> 6] = s;
  __syncthreads();
  if (threadIdx.x == 0) bsum[blockIdx.x] = wsum[0] + wsum[1] + wsum[2] + wsum[3];
}

__global__ __launch_bounds__(256) void k_scan2(const int* __restrict__ bsum, int* __restrict__ boff,
                                               int* __restrict__ rowptr) {
  int t = threadIdx.x;
  int lane = t & 63, wid = t >> 6;
  int v = (t < 200) ? bsum[t] : 0;
  int x = v;
#pragma unroll
  for (int off = 1; off < 64; off <<= 1) {
    int y = __shfl_up(x, off);
    if (lane >= off) x += y;
  }
  __shared__ int ws4[4];
  if (lane == 63) ws4[wid] = x;
  __syncthreads();
  int woff = 0;
  for (int k = 0; k < wid; ++k) woff += ws4[k];
  if (t < 200) boff[t] = woff + x - v;
  if (t == 255) rowptr[NN] = woff + x;  // grand total
}

__global__ __launch_bounds__(256) void k_scan3(const int* __restrict__ cnt, const int* __restrict__ boff,
                                               int* __restrict__ rowptr) {
  int i = blockIdx.x * 256 + threadIdx.x;
  int t = threadIdx.x;
  int lane = t & 63, wid = t >> 6;
  int v = cnt[i];
  int x = v;
#pragma unroll
  for (int off = 1; off < 64; off <<= 1) {
    int y = __shfl_up(x, off);
    if (lane >= off) x += y;
  }
  __shared__ int ws4[4];
  if (lane == 63) ws4[wid] = x;
  __syncthreads();
  int woff = boff[blockIdx.x];
  for (int k = 0; k < wid; ++k) woff += ws4[k];
  rowptr[i] = woff + x - v;
}

// ---- CSR fill, atomic-free: p = rowptr[dst] + rank[e] --------------------
__global__ void k_fill(const int* __restrict__ ei, const float* __restrict__ ew,
                       const float* __restrict__ dinv, const int* __restrict__ rowptr,
                       const int* __restrict__ rank, int2* __restrict__ csr) {
  int e = blockIdx.x * blockDim.x + threadIdx.x;
  if (e < NE) {
    int r = ei[e], c = ei[NE + e];
    int p = rowptr[c] + rank[e];
    float nw = dinv[r] * ew[e] * dinv[c];
    csr[p] = make_int2(r, __float_as_int(nw));
  }
}

// ---- fp32 GEMM: C[M,128](fp16) = A[M,K] @ W[K,128], 128x128 tile ---------
__global__ __launch_bounds__(256) void k_gemm(const float* __restrict__ A, const float* __restrict__ W,
                                              __half* __restrict__ C, int M, int K) {
  __shared__ float xs[8][128];  // transposed A tile: xs[k][m]
  __shared__ float ws[8][128];
  int tid = threadIdx.x;
  int tx = tid & 15, ty = tid >> 4;
  int bm = blockIdx.x * 128;
  float acc[8][8];
#pragma unroll
  for (int i = 0; i < 8; ++i)
#pragma unroll
    for (int j = 0; j < 8; ++j) acc[i][j] = 0.0f;

  int lm = tid >> 1;
  int lk = (tid & 1) * 4;
  int wk = tid >> 5;
  int wn = (tid & 31) * 4;

  for (int k0 = 0; k0 < K; k0 += 8) {
    float4 a4 = *(const float4*)(A + (size_t)(bm + lm) * K + k0 + lk);
    xs[lk + 0][lm] = a4.x;
    xs[lk + 1][lm] = a4.y;
    xs[lk + 2][lm] = a4.z;
    xs[lk + 3][lm] = a4.w;
    *(float4*)&ws[wk][wn] = *(const float4*)(W + (size_t)(k0 + wk) * 128 + wn);
    __syncthreads();
#pragma unroll
    for (int k = 0; k < 8; ++k) {
      float4 xa = *(const float4*)&xs[k][ty * 8];
      float4 xb = *(const float4*)&xs[k][ty * 8 + 4];
      float4 wa = *(const float4*)&ws[k][tx * 4];
      float4 wb = *(const float4*)&ws[k][64 + tx * 4];
      float xv[8] = {xa.x, xa.y, xa.z, xa.w, xb.x, xb.y, xb.z, xb.w};
      float wv[8] = {wa.x, wa.y, wa.z, wa.w, wb.x, wb.y, wb.z, wb.w};
#pragma unroll
      for (int i = 0; i < 8; ++i)
#pragma unroll
        for (int j = 0; j < 8; ++j) acc[i][j] += xv[i] * wv[j];
    }
    __syncthreads();
  }
#pragma unroll
  for (int i = 0; i < 8; ++i) {
    size_t rb = (size_t)(bm + ty * 8 + i) * 128;
    __half2 p0 = __floats2half2_rn(acc[i][0], acc[i][1]);
    __half2 p1 = __floats2half2_rn(acc[i][2], acc[i][3]);
    __half2 p2 = __floats2half2_rn(acc[i][4], acc[i][5]);
    __half2 p3 = __floats2half2_rn(acc[i][6], acc[i][7]);
    union { __half2 h[2]; uint2 u; } u0 = {{p0, p1}}, u1 = {{p2, p3}};
    *(uint2*)(C + rb + tx * 4) = u0.u;
    *(uint2*)(C + rb + 64 + tx * 4) = u1.u;
  }
}

// ---- CSR aggregation + bias + mish: one node per WAVE, half2 gathers -----
__global__ __launch_bounds__(256) void k_agg(const __half2* __restrict__ h, const int* __restrict__ rowptr,
                                             const int2* __restrict__ csr, const float* __restrict__ dinv,
                                             const float* __restrict__ bias, float* __restrict__ out) {
  int lane = threadIdx.x & 63;
  int n = blockIdx.x * 4 + (threadIdx.x >> 6);
  float di = dinv[n];
  float2 self = __half22float2(h[(size_t)n * 64 + lane]);
  float2 acc;
  acc.x = di * di * self.x;
  acc.y = di * di * self.y;
  int p0 = rowptr[n], p1 = rowptr[n + 1];
  int p = p0;
  for (; p + 1 < p1; p += 2) {
    int2 c0 = csr[p];
    int2 c1 = csr[p + 1];
    float2 f0 = __half22float2(h[(size_t)c0.x * 64 + lane]);
    float2 f1 = __half22float2(h[(size_t)c1.x * 64 + lane]);
    float w0 = __int_as_float(c0.y), w1 = __int_as_float(c1.y);
    acc.x += w0 * f0.x + w1 * f1.x;
    acc.y += w0 * f0.y + w1 * f1.y;
  }
  if (p < p1) {
    int2 c0 = csr[p];
    float2 f0 = __half22float2(h[(size_t)c0.x * 64 + lane]);
    float w0 = __int_as_float(c0.y);
    acc.x += w0 * f0.x;
    acc.y += w0 * f0.y;
  }
  float2 bb = *((const float2*)bias + lane);
  float2 o;
  o.x = mish_f(acc.x + bb.x);
  o.y = mish_f(acc.y + bb.y);
  *((float2*)out + (size_t)n * 64 + lane) = o;
}

// ---- readout: o8[n,k] = mish(h[n,:]@ro_w[:,k] + ro_b[k]) -----------------
__global__ __launch_bounds__(256) void k_ro(const float* __restrict__ h, const float* __restrict__ rw,
                                            const float* __restrict__ rb, float* __restrict__ o8) {
  __shared__ float w[128 * 8];
  int t = threadIdx.x;
  for (int i = t; i < 1024; i += 256) w[i] = rw[i];
  __syncthreads();
  int n = blockIdx.x * 32 + (t >> 3);
  int k = t & 7;
  const float* hr = h + (size_t)n * F;
  float acc = rb[k];
#pragma unroll 4
  for (int j = 0; j < 128; ++j) acc += hr[j] * w[j * 8 + k];
  o8[(size_t)n * 8 + k] = mish_f(acc);
}

// ---- fc1 split-K: z += feats[g, kc:kc+128] @ w[kc:kc+128, :] -------------
__global__ void k_fc1_init(const float* __restrict__ b, float* __restrict__ z) {
  int i = blockIdx.x * blockDim.x + threadIdx.x;
  if (i < 128 * 400) z[i] = b[i % 400];
}

__global__ __launch_bounds__(448) void k_fc1(const float* __restrict__ feats, const float* __restrict__ w,
                                             float* __restrict__ z) {
  __shared__ float fs[8][128];
  int t = threadIdx.x;
  int kc = blockIdx.x * 128;        // 25 chunks of 128 = 3200
  int g0 = blockIdx.y * 8;          // 16 groups of 8 = 128 graphs
  for (int i = t; i < 1024; i += 448) {
    int g = i >> 7, k = i & 127;
    fs[g][k] = feats[(size_t)(g0 + g) * 3200 + kc + k];
  }
  __syncthreads();
  if (t < 400) {
    float a[8];
#pragma unroll
    for (int g = 0; g < 8; ++g) a[g] = 0.0f;
    for (int k = 0; k < 128; ++k) {
      float wv = w[(size_t)(kc + k) * 400 + t];
#pragma unroll
      for (int g = 0; g < 8; ++g) a[g] += fs[g][k] * wv;
    }
#pragma unroll
    for (int g = 0; g < 8; ++g) atomicAdd(&z[(size_t)(g0 + g) * 400 + t], a[g]);
  }
}

// ---- batchnorm stats (training-mode, biased var) -> scale/shift ----------
__global__ void k_bn(const float* __restrict__ z, const float* __restrict__ gamma,
                     const float* __restrict__ beta, float* __restrict__ gs, float* __restrict__ gb) {
  int j = blockIdx.x * blockDim.x + threadIdx.x;
  if (j < 400) {
    float s = 0.f;
    for (int b = 0; b < 128; ++b) s += z[b * 400 + j];
    float mu = s * (1.0f / 128.0f);
    float v = 0.f;
    for (int b = 0; b < 128; ++b) {
      float d = z[b * 400 + j] - mu;
      v += d * d;
    }
    v *= (1.0f / 128.0f);
    float rs = rsqrtf(v + 1e-5f);
    float g = gamma[j] * rs;
    gs[j] = g;
    gb[j] = beta[j] - mu * g;
  }
}

// ---- fc2: logits[b,c] = mish(zn[b,:]) @ fc2_w[:,c] + fc2_b[c] ------------
__global__ __launch_bounds__(256) void k_fc2(const float* __restrict__ z, const float* __restrict__ gs,
                                             const float* __restrict__ gb, const float* __restrict__ w2,
                                             const float* __restrict__ b2, float* __restrict__ out) {
  int t = threadIdx.x;
  int bg = t >> 1, c = t & 1;
  float acc = b2[c];
  for (int j = 0; j < 400; ++j) {
    float zn = z[bg * 400 + j] * gs[j] + gb[j];
    acc += mish_f(zn) * w2[j * 2 + c];
  }
  out[bg * 2 + c] = acc;
}

extern "C" void kernel_launch(void* const* d_in, const int* in_sizes, int n_in,
                              void* d_out, int out_size, void* d_ws, size_t ws_size,
                              hipStream_t stream) {
  (void)in_sizes; (void)n_in; (void)out_size; (void)ws_size;
  const float* x   = (const float*)d_in[0];
  const int*   ei  = (const int*)d_in[1];
  const float* ew  = (const float*)d_in[2];
  const float* c1w = (const float*)d_in[4];
  const float* c1b = (const float*)d_in[5];
  const float* c2w = (const float*)d_in[6];
  const float* c2b = (const float*)d_in[7];
  const float* rw  = (const float*)d_in[8];
  const float* rb  = (const float*)d_in[9];
  const float* f1w = (const float*)d_in[10];
  const float* f1b = (const float*)d_in[11];
  const float* bng = (const float*)d_in[12];
  const float* bnb = (const float*)d_in[13];
  const float* f2w = (const float*)d_in[14];
  const float* f2b = (const float*)d_in[15];
  float* out = (float*)d_out;

  char* ws = (char*)d_ws;
  size_t off = 0;
  auto alloc = [&](size_t bytes) {
    void* p = ws + off;
    off = (off + bytes + 255) & ~(size_t)255;
    return p;
  };
  unsigned long long* acc64 = (unsigned long long*)alloc((size_t)NN * 8);
  float* dinv   = (float*)alloc((size_t)NN * 4);
  int*   cnt    = (int*)alloc((size_t)NN * 4);
  int*   rowptr = (int*)alloc((size_t)(NN + 1) * 4);
  int*   rank   = (int*)alloc((size_t)NE * 4);
  int*   bsum   = (int*)alloc(200 * 4);
  int*   boff   = (int*)alloc(200 * 4);
  int2*  csr    = (int2*)alloc((size_t)NE * 8);
  __half* bufA  = (__half*)alloc((size_t)NN * F * 2);  // h pre-agg (fp16)
  float* bufB   = (float*)alloc((size_t)NN * F * 4);   // h post-agg+mish
  float* o8     = (float*)alloc((size_t)NN * 8 * 4);
  float* z      = (float*)alloc((size_t)128 * 400 * 4);
  float* gs     = (float*)alloc(400 * 4);
  float* gb     = (float*)alloc(400 * 4);

  hipMemsetAsync(acc64, 0, (size_t)NN * 8, stream);

  k_edge_cnt<<<(NE + 255) / 256, 256, 0, stream>>>(ei, ew, acc64, rank);
  k_dinv<<<(NN + 255) / 256, 256, 0, stream>>>(acc64, dinv, cnt);
  k_scan1<<<NN / 256, 256, 0, stream>>>(cnt, bsum);
  k_scan2<<<1, 256, 0, stream>>>(bsum, boff, rowptr);
  k_scan3<<<NN / 256, 256, 0, stream>>>(cnt, boff, rowptr);
  k_fill<<<(NE + 255) / 256, 256, 0, stream>>>(ei, ew, dinv, rowptr, rank, csr);

  // conv1: h = x@W1 (fp16 out) ; agg+bias+mish (fp32 out)
  k_gemm<<<NN / 128, 256, 0, stream>>>(x, c1w, bufA, NN, 400);
  k_agg<<<NN / 4, 256, 0, stream>>>((const __half2*)bufA, rowptr, csr, dinv, c1b, bufB);
  // conv2
  k_gemm<<<NN / 128, 256, 0, stream>>>(bufB, c2w, bufA, NN, 128);
  k_agg<<<NN / 4, 256, 0, stream>>>((const __half2*)bufA, rowptr, csr, dinv, c2b, bufB);
  // readout -> feats (o8 flat IS feats[128][3200])
  k_ro<<<NN / 32, 256, 0, stream>>>(bufB, rw, rb, o8);
  k_fc1_init<<<(128 * 400 + 255) / 256, 256, 0, stream>>>(f1b, z);
  {
    dim3 g(25, 16);
    k_fc1<<<g, 448, 0, stream>>>(o8, f1w, z);
  }
  k_bn<<<2, 256, 0, stream>>>(z, bng, bnb, gs, gb);
  k_fc2<<<1, 256, 0, stream>>>(z, gs, gb, f2w, f2b, out);
}

// Round 5
// 623.724 us; speedup vs baseline: 2.0982x; 1.2528x over previous
//
#include <hip/hip_runtime.h>
#include <hip/hip_fp16.h>
#include <math.h>

#define NN 51200
#define NE 2048000
#define F 128

typedef _Float16 half8 __attribute__((ext_vector_type(8)));
typedef float floatx4 __attribute__((ext_vector_type(4)));

__device__ __forceinline__ float mish_f(float x) {
  if (x > 20.0f) return x;
  float e = __expf(x);
  float w = 1.0f + e;
  w = w * w;
  return x * (w - 1.0f) / (w + 1.0f);
}

// ---- single packed atomic per edge: hi24=count, lo40=fixed-point ew sum --
__global__ void k_edge_cnt(const int* __restrict__ ei, const float* __restrict__ ew,
                           unsigned long long* __restrict__ acc, int* __restrict__ rank) {
  int e = blockIdx.x * blockDim.x + threadIdx.x;
  if (e < NE) {
    int c = ei[NE + e];
    unsigned long long fx = (unsigned long long)(unsigned)(ew[e] * 16777216.0f + 0.5f);
    unsigned long long old = atomicAdd(&acc[c], (1ULL << 40) | fx);
    rank[e] = (int)(old >> 40);
  }
}

// ---- unpack: dinv = rsqrt(deg+1), cnt for scan ---------------------------
__global__ void k_dinv(const unsigned long long* __restrict__ acc, float* __restrict__ dinv,
                       int* __restrict__ cnt) {
  int i = blockIdx.x * blockDim.x + threadIdx.x;
  if (i < NN) {
    unsigned long long v = acc[i];
    cnt[i] = (int)(v >> 40);
    double deg = (double)(v & ((1ULL << 40) - 1)) * (1.0 / 16777216.0);
    dinv[i] = rsqrtf((float)deg + 1.0f);  // +1 = self-loop weight
  }
}

// ---- hierarchical exclusive scan of cnt -> rowptr ------------------------
__global__ __launch_bounds__(256) void k_scan1(const int* __restrict__ cnt, int* __restrict__ bsum) {
  int i = blockIdx.x * 256 + threadIdx.x;
  int s = cnt[i];
#pragma unroll
  for (int off = 1; off < 64; off <<= 1) s += __shfl_xor(s, off);
  __shared__ int wsum[4];
  if ((threadIdx.x & 63) == 0) wsum[threadIdx.x >> 6] = s;
  __syncthreads();
  if (threadIdx.x == 0) bsum[blockIdx.x] = wsum[0] + wsum[1] + wsum[2] + wsum[3];
}

__global__ __launch_bounds__(256) void k_scan2(const int* __restrict__ bsum, int* __restrict__ boff,
                                               int* __restrict__ rowptr) {
  int t = threadIdx.x;
  int lane = t & 63, wid = t >> 6;
  int v = (t < 200) ? bsum[t] : 0;
  int x = v;
#pragma unroll
  for (int off = 1; off < 64; off <<= 1) {
    int y = __shfl_up(x, off);
    if (lane >= off) x += y;
  }
  __shared__ int ws4[4];
  if (lane == 63) ws4[wid] = x;
  __syncthreads();
  int woff = 0;
  for (int k = 0; k < wid; ++k) woff += ws4[k];
  if (t < 200) boff[t] = woff + x - v;
  if (t == 255) rowptr[NN] = woff + x;  // grand total
}

__global__ __launch_bounds__(256) void k_scan3(const int* __restrict__ cnt, const int* __restrict__ boff,
                                               int* __restrict__ rowptr) {
  int i = blockIdx.x * 256 + threadIdx.x;
  int t = threadIdx.x;
  int lane = t & 63, wid = t >> 6;
  int v = cnt[i];
  int x = v;
#pragma unroll
  for (int off = 1; off < 64; off <<= 1) {
    int y = __shfl_up(x, off);
    if (lane >= off) x += y;
  }
  __shared__ int ws4[4];
  if (lane == 63) ws4[wid] = x;
  __syncthreads();
  int woff = boff[blockIdx.x];
  for (int k = 0; k < wid; ++k) woff += ws4[k];
  rowptr[i] = woff + x - v;
}

// ---- CSR fill, atomic-free: p = rowptr[dst] + rank[e] --------------------
__global__ void k_fill(const int* __restrict__ ei, const float* __restrict__ ew,
                       const float* __restrict__ dinv, const int* __restrict__ rowptr,
                       const int* __restrict__ rank, int2* __restrict__ csr) {
  int e = blockIdx.x * blockDim.x + threadIdx.x;
  if (e < NE) {
    int r = ei[e], c = ei[NE + e];
    int p = rowptr[c] + rank[e];
    float nw = dinv[r] * ew[e] * dinv[c];
    csr[p] = make_int2(r, __float_as_int(nw));
  }
}

// ---- W[K][128] fp32 -> Wt[128][K] fp16 -----------------------------------
__global__ void k_prep_w(const float* __restrict__ W, _Float16* __restrict__ Wt, int K) {
  int idx = blockIdx.x * blockDim.x + threadIdx.x;
  if (idx < K * 128) {
    int k = idx >> 7, n = idx & 127;
    Wt[n * K + k] = (_Float16)W[idx];
  }
}

// ---- MFMA GEMM: C[M,128](fp16) = A[M,K] @ W[K,128] -----------------------
// Block: 256 thr = 4 waves, tile 128(M)x128(N), K-chunks of 32.
// LDS rows padded to 40 halves (stride 20 banks -> only 2-way conflicts).
// Fragment layouts (HW-verified, guide §3): A[m=lane&15][k=quad*8+j],
// B[k=quad*8+j][n=lane&15], C/D col=lane&15 row=quad*4+reg.
template <bool A_IS_F32>
__global__ __launch_bounds__(256) void k_gemm16(const void* __restrict__ Av,
                                                const _Float16* __restrict__ Wt,
                                                __half* __restrict__ C, int K) {
  __shared__ _Float16 As[128][40];
  __shared__ _Float16 Bs[128][40];
  int t = threadIdx.x;
  int bm = blockIdx.x * 128;
  int w = t >> 6, l = t & 63, rr = l & 15, q = l >> 4;
  int si = t >> 1, sj = (t & 1) * 16;

  floatx4 acc[2][8];
#pragma unroll
  for (int a = 0; a < 2; ++a)
#pragma unroll
    for (int b = 0; b < 8; ++b) acc[a][b] = (floatx4){0.f, 0.f, 0.f, 0.f};

  for (int k0 = 0; k0 < K; k0 += 32) {
    // stage A tile (convert fp32->fp16 if needed)
    if (A_IS_F32) {
      const float* A = (const float*)Av;
      half8 h0, h1;
      if (k0 + sj < K) {
        const float* ap = A + (size_t)(bm + si) * K + k0 + sj;
        float4 v0 = *(const float4*)(ap + 0);
        float4 v1 = *(const float4*)(ap + 4);
        float4 v2 = *(const float4*)(ap + 8);
        float4 v3 = *(const float4*)(ap + 12);
        h0 = (half8){(_Float16)v0.x, (_Float16)v0.y, (_Float16)v0.z, (_Float16)v0.w,
                     (_Float16)v1.x, (_Float16)v1.y, (_Float16)v1.z, (_Float16)v1.w};
        h1 = (half8){(_Float16)v2.x, (_Float16)v2.y, (_Float16)v2.z, (_Float16)v2.w,
                     (_Float16)v3.x, (_Float16)v3.y, (_Float16)v3.z, (_Float16)v3.w};
      } else {
        h0 = (half8){0, 0, 0, 0, 0, 0, 0, 0};
        h1 = h0;
      }
      *(half8*)&As[si][sj] = h0;
      *(half8*)&As[si][sj + 8] = h1;
    } else {
      const __half* A = (const __half*)Av;
      uint4 u0, u1;
      if (k0 + sj < K) {
        const __half* ap = A + (size_t)(bm + si) * K + k0 + sj;
        u0 = *(const uint4*)ap;
        u1 = *(const uint4*)(ap + 8);
      } else {
        u0 = make_uint4(0, 0, 0, 0);
        u1 = u0;
      }
      *(uint4*)&As[si][sj] = u0;
      *(uint4*)&As[si][sj + 8] = u1;
    }
    // stage Wt tile
    {
      uint4 u0, u1;
      if (k0 + sj < K) {
        const _Float16* wp = Wt + (size_t)si * K + k0 + sj;
        u0 = *(const uint4*)wp;
        u1 = *(const uint4*)(wp + 8);
      } else {
        u0 = make_uint4(0, 0, 0, 0);
        u1 = u0;
      }
      *(uint4*)&Bs[si][sj] = u0;
      *(uint4*)&Bs[si][sj + 8] = u1;
    }
    __syncthreads();

    half8 a0 = *(const half8*)&As[w * 32 + rr][q * 8];
    half8 a1 = *(const half8*)&As[w * 32 + 16 + rr][q * 8];
#pragma unroll
    for (int nt = 0; nt < 8; ++nt) {
      half8 b = *(const half8*)&Bs[nt * 16 + rr][q * 8];
      acc[0][nt] = __builtin_amdgcn_mfma_f32_16x16x32_f16(a0, b, acc[0][nt], 0, 0, 0);
      acc[1][nt] = __builtin_amdgcn_mfma_f32_16x16x32_f16(a1, b, acc[1][nt], 0, 0, 0);
    }
    __syncthreads();
  }
#pragma unroll
  for (int mt = 0; mt < 2; ++mt)
#pragma unroll
    for (int nt = 0; nt < 8; ++nt)
#pragma unroll
      for (int r4 = 0; r4 < 4; ++r4) {
        int row = bm + w * 32 + mt * 16 + q * 4 + r4;
        C[(size_t)row * 128 + nt * 16 + rr] = __float2half(acc[mt][nt][r4]);
      }
}

// ---- CSR aggregation + bias + mish: one node per WAVE, unroll 8 ----------
__global__ __launch_bounds__(256) void k_agg(const __half2* __restrict__ h, const int* __restrict__ rowptr,
                                             const int2* __restrict__ csr, const float* __restrict__ dinv,
                                             const float* __restrict__ bias, __half2* __restrict__ out) {
  int lane = threadIdx.x & 63;
  int n = blockIdx.x * 4 + (threadIdx.x >> 6);
  float di = dinv[n];
  float2 self = __half22float2(h[(size_t)n * 64 + lane]);
  float ax = di * di * self.x, ay = di * di * self.y;
  int p = rowptr[n], p1 = rowptr[n + 1];
  for (; p + 8 <= p1; p += 8) {
    int2 c[8];
#pragma unroll
    for (int u = 0; u < 8; ++u) c[u] = csr[p + u];
    float2 f[8];
#pragma unroll
    for (int u = 0; u < 8; ++u) f[u] = __half22float2(h[(size_t)c[u].x * 64 + lane]);
#pragma unroll
    for (int u = 0; u < 8; ++u) {
      float w = __int_as_float(c[u].y);
      ax += w * f[u].x;
      ay += w * f[u].y;
    }
  }
  for (; p < p1; ++p) {
    int2 c0 = csr[p];
    float2 f0 = __half22float2(h[(size_t)c0.x * 64 + lane]);
    float w = __int_as_float(c0.y);
    ax += w * f0.x;
    ay += w * f0.y;
  }
  float2 bb = ((const float2*)bias)[lane];
  out[(size_t)n * 64 + lane] = __floats2half2_rn(mish_f(ax + bb.x), mish_f(ay + bb.y));
}

// ---- readout (fp16 h): o8[n,k] = mish(h[n,:]@ro_w[:,k] + ro_b[k]) --------
__global__ __launch_bounds__(256) void k_ro(const __half2* __restrict__ h, const float* __restrict__ rw,
                                            const float* __restrict__ rb, float* __restrict__ o8) {
  __shared__ float w[128 * 8];
  int t = threadIdx.x;
  for (int i = t; i < 1024; i += 256) w[i] = rw[i];
  __syncthreads();
  int n = blockIdx.x * 32 + (t >> 3);
  int k = t & 7;
  const __half2* hr = h + (size_t)n * 64;
  float acc = rb[k];
#pragma unroll 4
  for (int j = 0; j < 64; ++j) {
    float2 hv = __half22float2(hr[j]);
    acc += hv.x * w[(2 * j) * 8 + k] + hv.y * w[(2 * j + 1) * 8 + k];
  }
  o8[(size_t)n * 8 + k] = mish_f(acc);
}

// ---- fc1 split-K: z += feats[g, kc:kc+128] @ w[kc:kc+128, :] -------------
__global__ void k_fc1_init(const float* __restrict__ b, float* __restrict__ z) {
  int i = blockIdx.x * blockDim.x + threadIdx.x;
  if (i < 128 * 400) z[i] = b[i % 400];
}

__global__ __launch_bounds__(448) void k_fc1(const float* __restrict__ feats, const float* __restrict__ w,
                                             float* __restrict__ z) {
  __shared__ float fs[8][128];
  int t = threadIdx.x;
  int kc = blockIdx.x * 128;
  int g0 = blockIdx.y * 8;
  for (int i = t; i < 1024; i += 448) {
    int g = i >> 7, k = i & 127;
    fs[g][k] = feats[(size_t)(g0 + g) * 3200 + kc + k];
  }
  __syncthreads();
  if (t < 400) {
    float a[8];
#pragma unroll
    for (int g = 0; g < 8; ++g) a[g] = 0.0f;
    for (int k = 0; k < 128; ++k) {
      float wv = w[(size_t)(kc + k) * 400 + t];
#pragma unroll
      for (int g = 0; g < 8; ++g) a[g] += fs[g][k] * wv;
    }
#pragma unroll
    for (int g = 0; g < 8; ++g) atomicAdd(&z[(size_t)(g0 + g) * 400 + t], a[g]);
  }
}

// ---- batchnorm stats (training-mode, biased var) -> scale/shift ----------
__global__ void k_bn(const float* __restrict__ z, const float* __restrict__ gamma,
                     const float* __restrict__ beta, float* __restrict__ gs, float* __restrict__ gb) {
  int j = blockIdx.x * blockDim.x + threadIdx.x;
  if (j < 400) {
    float s = 0.f;
    for (int b = 0; b < 128; ++b) s += z[b * 400 + j];
    float mu = s * (1.0f / 128.0f);
    float v = 0.f;
    for (int b = 0; b < 128; ++b) {
      float d = z[b * 400 + j] - mu;
      v += d * d;
    }
    v *= (1.0f / 128.0f);
    float rs = rsqrtf(v + 1e-5f);
    float g = gamma[j] * rs;
    gs[j] = g;
    gb[j] = beta[j] - mu * g;
  }
}

// ---- fc2: logits[b,c] = mish(zn[b,:]) @ fc2_w[:,c] + fc2_b[c] ------------
__global__ __launch_bounds__(256) void k_fc2(const float* __restrict__ z, const float* __restrict__ gs,
                                             const float* __restrict__ gb, const float* __restrict__ w2,
                                             const float* __restrict__ b2, float* __restrict__ out) {
  int t = threadIdx.x;
  int bg = t >> 1, c = t & 1;
  float acc = b2[c];
  for (int j = 0; j < 400; ++j) {
    float zn = z[bg * 400 + j] * gs[j] + gb[j];
    acc += mish_f(zn) * w2[j * 2 + c];
  }
  out[bg * 2 + c] = acc;
}

extern "C" void kernel_launch(void* const* d_in, const int* in_sizes, int n_in,
                              void* d_out, int out_size, void* d_ws, size_t ws_size,
                              hipStream_t stream) {
  (void)in_sizes; (void)n_in; (void)out_size; (void)ws_size;
  const float* x   = (const float*)d_in[0];
  const int*   ei  = (const int*)d_in[1];
  const float* ew  = (const float*)d_in[2];
  const float* c1w = (const float*)d_in[4];
  const float* c1b = (const float*)d_in[5];
  const float* c2w = (const float*)d_in[6];
  const float* c2b = (const float*)d_in[7];
  const float* rw  = (const float*)d_in[8];
  const float* rb  = (const float*)d_in[9];
  const float* f1w = (const float*)d_in[10];
  const float* f1b = (const float*)d_in[11];
  const float* bng = (const float*)d_in[12];
  const float* bnb = (const float*)d_in[13];
  const float* f2w = (const float*)d_in[14];
  const float* f2b = (const float*)d_in[15];
  float* out = (float*)d_out;

  char* ws = (char*)d_ws;
  size_t off = 0;
  auto alloc = [&](size_t bytes) {
    void* p = ws + off;
    off = (off + bytes + 255) & ~(size_t)255;
    return p;
  };
  unsigned long long* acc64 = (unsigned long long*)alloc((size_t)NN * 8);
  float* dinv   = (float*)alloc((size_t)NN * 4);
  int*   cnt    = (int*)alloc((size_t)NN * 4);
  int*   rowptr = (int*)alloc((size_t)(NN + 1) * 4);
  int*   rank   = (int*)alloc((size_t)NE * 4);
  int*   bsum   = (int*)alloc(200 * 4);
  int*   boff   = (int*)alloc(200 * 4);
  int2*  csr    = (int2*)alloc((size_t)NE * 8);
  __half* A1    = (__half*)alloc((size_t)NN * F * 2);  // gemm out (fp16)
  __half* B1    = (__half*)alloc((size_t)NN * F * 2);  // agg out (fp16)
  _Float16* Wt1 = (_Float16*)alloc((size_t)400 * 128 * 2);
  _Float16* Wt2 = (_Float16*)alloc((size_t)128 * 128 * 2);
  float* o8     = (float*)alloc((size_t)NN * 8 * 4);
  float* z      = (float*)alloc((size_t)128 * 400 * 4);
  float* gs     = (float*)alloc(400 * 4);
  float* gb     = (float*)alloc(400 * 4);

  hipMemsetAsync(acc64, 0, (size_t)NN * 8, stream);

  k_prep_w<<<(400 * 128 + 255) / 256, 256, 0, stream>>>(c1w, Wt1, 400);
  k_prep_w<<<(128 * 128 + 255) / 256, 256, 0, stream>>>(c2w, Wt2, 128);
  k_edge_cnt<<<(NE + 255) / 256, 256, 0, stream>>>(ei, ew, acc64, rank);
  k_dinv<<<(NN + 255) / 256, 256, 0, stream>>>(acc64, dinv, cnt);
  k_scan1<<<NN / 256, 256, 0, stream>>>(cnt, bsum);
  k_scan2<<<1, 256, 0, stream>>>(bsum, boff, rowptr);
  k_scan3<<<NN / 256, 256, 0, stream>>>(cnt, boff, rowptr);
  k_fill<<<(NE + 255) / 256, 256, 0, stream>>>(ei, ew, dinv, rowptr, rank, csr);

  // conv1: h = x@W1 (MFMA, fp16 out) ; agg+bias+mish (fp16 out)
  k_gemm16<true><<<NN / 128, 256, 0, stream>>>(x, Wt1, A1, 400);
  k_agg<<<NN / 4, 256, 0, stream>>>((const __half2*)A1, rowptr, csr, dinv, c1b, (__half2*)B1);
  // conv2
  k_gemm16<false><<<NN / 128, 256, 0, stream>>>(B1, Wt2, A1, 128);
  k_agg<<<NN / 4, 256, 0, stream>>>((const __half2*)A1, rowptr, csr, dinv, c2b, (__half2*)B1);
  // readout -> feats (o8 flat IS feats[128][3200])
  k_ro<<<NN / 32, 256, 0, stream>>>((const __half2*)B1, rw, rb, o8);
  k_fc1_init<<<(128 * 400 + 255) / 256, 256, 0, stream>>>(f1b, z);
  {
    dim3 g(25, 16);
    k_fc1<<<g, 448, 0, stream>>>(o8, f1w, z);
  }
  k_bn<<<2, 256, 0, stream>>>(z, bng, bnb, gs, gb);
  k_fc2<<<1, 256, 0, stream>>>(z, gs, gb, f2w, f2b, out);
}

// Round 6
// 535.699 us; speedup vs baseline: 2.4430x; 1.1643x over previous
//
#include <hip/hip_runtime.h>
#include <hip/hip_fp16.h>
#include <math.h>

#define NN 51200
#define NE 2048000
#define F 128

typedef _Float16 half8 __attribute__((ext_vector_type(8)));
typedef float floatx4 __attribute__((ext_vector_type(4)));

__device__ __forceinline__ float mish_f(float x) {
  if (x > 20.0f) return x;
  float e = __expf(x);
  float w = 1.0f + e;
  w = w * w;
  return x * (w - 1.0f) / (w + 1.0f);
}

// ---- single packed atomic per edge: hi24=count, lo40=fixed-point ew sum --
__global__ void k_edge_cnt(const int* __restrict__ ei, const float* __restrict__ ew,
                           unsigned long long* __restrict__ acc, int* __restrict__ rank) {
  int e = blockIdx.x * blockDim.x + threadIdx.x;
  if (e < NE) {
    int c = ei[NE + e];
    unsigned long long fx = (unsigned long long)(unsigned)(ew[e] * 16777216.0f + 0.5f);
    unsigned long long old = atomicAdd(&acc[c], (1ULL << 40) | fx);
    rank[e] = (int)(old >> 40);
  }
}

// ---- unpack: dinv = rsqrt(deg+1), cnt for scan ---------------------------
__global__ void k_dinv(const unsigned long long* __restrict__ acc, float* __restrict__ dinv,
                       int* __restrict__ cnt) {
  int i = blockIdx.x * blockDim.x + threadIdx.x;
  if (i < NN) {
    unsigned long long v = acc[i];
    cnt[i] = (int)(v >> 40);
    double deg = (double)(v & ((1ULL << 40) - 1)) * (1.0 / 16777216.0);
    dinv[i] = rsqrtf((float)deg + 1.0f);  // +1 = self-loop weight
  }
}

// ---- hierarchical exclusive scan of cnt -> rowptr ------------------------
__global__ __launch_bounds__(256) void k_scan1(const int* __restrict__ cnt, int* __restrict__ bsum) {
  int i = blockIdx.x * 256 + threadIdx.x;
  int s = cnt[i];
#pragma unroll
  for (int off = 1; off < 64; off <<= 1) s += __shfl_xor(s, off);
  __shared__ int wsum[4];
  if ((threadIdx.x & 63) == 0) wsum[threadIdx.x >> 6] = s;
  __syncthreads();
  if (threadIdx.x == 0) bsum[blockIdx.x] = wsum[0] + wsum[1] + wsum[2] + wsum[3];
}

__global__ __launch_bounds__(256) void k_scan2(const int* __restrict__ bsum, int* __restrict__ boff,
                                               int* __restrict__ rowptr) {
  int t = threadIdx.x;
  int lane = t & 63, wid = t >> 6;
  int v = (t < 200) ? bsum[t] : 0;
  int x = v;
#pragma unroll
  for (int off = 1; off < 64; off <<= 1) {
    int y = __shfl_up(x, off);
    if (lane >= off) x += y;
  }
  __shared__ int ws4[4];
  if (lane == 63) ws4[wid] = x;
  __syncthreads();
  int woff = 0;
  for (int k = 0; k < wid; ++k) woff += ws4[k];
  if (t < 200) boff[t] = woff + x - v;
  if (t == 255) rowptr[NN] = woff + x;  // grand total
}

__global__ __launch_bounds__(256) void k_scan3(const int* __restrict__ cnt, const int* __restrict__ boff,
                                               int* __restrict__ rowptr) {
  int i = blockIdx.x * 256 + threadIdx.x;
  int t = threadIdx.x;
  int lane = t & 63, wid = t >> 6;
  int v = cnt[i];
  int x = v;
#pragma unroll
  for (int off = 1; off < 64; off <<= 1) {
    int y = __shfl_up(x, off);
    if (lane >= off) x += y;
  }
  __shared__ int ws4[4];
  if (lane == 63) ws4[wid] = x;
  __syncthreads();
  int woff = boff[blockIdx.x];
  for (int k = 0; k < wid; ++k) woff += ws4[k];
  rowptr[i] = woff + x - v;
}

// ---- CSR fill, atomic-free: p = rowptr[dst] + rank[e] --------------------
__global__ void k_fill(const int* __restrict__ ei, const float* __restrict__ ew,
                       const float* __restrict__ dinv, const int* __restrict__ rowptr,
                       const int* __restrict__ rank, int2* __restrict__ csr) {
  int e = blockIdx.x * blockDim.x + threadIdx.x;
  if (e < NE) {
    int r = ei[e], c = ei[NE + e];
    int p = rowptr[c] + rank[e];
    float nw = dinv[r] * ew[e] * dinv[c];
    csr[p] = make_int2(r, __float_as_int(nw));
  }
}

// ---- W[K][128] fp32 -> Wt[128][K] fp16 -----------------------------------
__global__ void k_prep_w(const float* __restrict__ W, _Float16* __restrict__ Wt, int K) {
  int idx = blockIdx.x * blockDim.x + threadIdx.x;
  if (idx < K * 128) {
    int k = idx >> 7, n = idx & 127;
    Wt[n * K + k] = (_Float16)W[idx];
  }
}

// ---- MFMA GEMM: C[M,128](fp16) = A[M,K] @ W[K,128] -----------------------
template <bool A_IS_F32>
__global__ __launch_bounds__(256) void k_gemm16(const void* __restrict__ Av,
                                                const _Float16* __restrict__ Wt,
                                                __half* __restrict__ C, int K) {
  __shared__ _Float16 As[128][40];
  __shared__ _Float16 Bs[128][40];
  int t = threadIdx.x;
  int bm = blockIdx.x * 128;
  int w = t >> 6, l = t & 63, rr = l & 15, q = l >> 4;
  int si = t >> 1, sj = (t & 1) * 16;

  floatx4 acc[2][8];
#pragma unroll
  for (int a = 0; a < 2; ++a)
#pragma unroll
    for (int b = 0; b < 8; ++b) acc[a][b] = (floatx4){0.f, 0.f, 0.f, 0.f};

  for (int k0 = 0; k0 < K; k0 += 32) {
    if (A_IS_F32) {
      const float* A = (const float*)Av;
      half8 h0, h1;
      if (k0 + sj < K) {
        const float* ap = A + (size_t)(bm + si) * K + k0 + sj;
        float4 v0 = *(const float4*)(ap + 0);
        float4 v1 = *(const float4*)(ap + 4);
        float4 v2 = *(const float4*)(ap + 8);
        float4 v3 = *(const float4*)(ap + 12);
        h0 = (half8){(_Float16)v0.x, (_Float16)v0.y, (_Float16)v0.z, (_Float16)v0.w,
                     (_Float16)v1.x, (_Float16)v1.y, (_Float16)v1.z, (_Float16)v1.w};
        h1 = (half8){(_Float16)v2.x, (_Float16)v2.y, (_Float16)v2.z, (_Float16)v2.w,
                     (_Float16)v3.x, (_Float16)v3.y, (_Float16)v3.z, (_Float16)v3.w};
      } else {
        h0 = (half8){0, 0, 0, 0, 0, 0, 0, 0};
        h1 = h0;
      }
      *(half8*)&As[si][sj] = h0;
      *(half8*)&As[si][sj + 8] = h1;
    } else {
      const __half* A = (const __half*)Av;
      uint4 u0, u1;
      if (k0 + sj < K) {
        const __half* ap = A + (size_t)(bm + si) * K + k0 + sj;
        u0 = *(const uint4*)ap;
        u1 = *(const uint4*)(ap + 8);
      } else {
        u0 = make_uint4(0, 0, 0, 0);
        u1 = u0;
      }
      *(uint4*)&As[si][sj] = u0;
      *(uint4*)&As[si][sj + 8] = u1;
    }
    {
      uint4 u0, u1;
      if (k0 + sj < K) {
        const _Float16* wp = Wt + (size_t)si * K + k0 + sj;
        u0 = *(const uint4*)wp;
        u1 = *(const uint4*)(wp + 8);
      } else {
        u0 = make_uint4(0, 0, 0, 0);
        u1 = u0;
      }
      *(uint4*)&Bs[si][sj] = u0;
      *(uint4*)&Bs[si][sj + 8] = u1;
    }
    __syncthreads();

    half8 a0 = *(const half8*)&As[w * 32 + rr][q * 8];
    half8 a1 = *(const half8*)&As[w * 32 + 16 + rr][q * 8];
#pragma unroll
    for (int nt = 0; nt < 8; ++nt) {
      half8 b = *(const half8*)&Bs[nt * 16 + rr][q * 8];
      acc[0][nt] = __builtin_amdgcn_mfma_f32_16x16x32_f16(a0, b, acc[0][nt], 0, 0, 0);
      acc[1][nt] = __builtin_amdgcn_mfma_f32_16x16x32_f16(a1, b, acc[1][nt], 0, 0, 0);
    }
    __syncthreads();
  }
#pragma unroll
  for (int mt = 0; mt < 2; ++mt)
#pragma unroll
    for (int nt = 0; nt < 8; ++nt)
#pragma unroll
      for (int r4 = 0; r4 < 4; ++r4) {
        int row = bm + w * 32 + mt * 16 + q * 4 + r4;
        C[(size_t)row * 128 + nt * 16 + rr] = __float2half(acc[mt][nt][r4]);
      }
}

// ---- CSR aggregation + bias + mish: one node per WAVE, unroll 8 ----------
__global__ __launch_bounds__(256) void k_agg(const __half2* __restrict__ h, const int* __restrict__ rowptr,
                                             const int2* __restrict__ csr, const float* __restrict__ dinv,
                                             const float* __restrict__ bias, __half2* __restrict__ out) {
  int lane = threadIdx.x & 63;
  int n = blockIdx.x * 4 + (threadIdx.x >> 6);
  float di = dinv[n];
  float2 self = __half22float2(h[(size_t)n * 64 + lane]);
  float ax = di * di * self.x, ay = di * di * self.y;
  int p = rowptr[n], p1 = rowptr[n + 1];
  for (; p + 8 <= p1; p += 8) {
    int2 c[8];
#pragma unroll
    for (int u = 0; u < 8; ++u) c[u] = csr[p + u];
    float2 f[8];
#pragma unroll
    for (int u = 0; u < 8; ++u) f[u] = __half22float2(h[(size_t)c[u].x * 64 + lane]);
#pragma unroll
    for (int u = 0; u < 8; ++u) {
      float w = __int_as_float(c[u].y);
      ax += w * f[u].x;
      ay += w * f[u].y;
    }
  }
  for (; p < p1; ++p) {
    int2 c0 = csr[p];
    float2 f0 = __half22float2(h[(size_t)c0.x * 64 + lane]);
    float w = __int_as_float(c0.y);
    ax += w * f0.x;
    ay += w * f0.y;
  }
  float2 bb = ((const float2*)bias)[lane];
  out[(size_t)n * 64 + lane] = __floats2half2_rn(mish_f(ax + bb.x), mish_f(ay + bb.y));
}

// ---- readout (fp16 h): o8[n,k] = mish(h[n,:]@ro_w[:,k] + ro_b[k]) --------
__global__ __launch_bounds__(256) void k_ro(const __half2* __restrict__ h, const float* __restrict__ rw,
                                            const float* __restrict__ rb, float* __restrict__ o8) {
  __shared__ float w[128 * 8];
  int t = threadIdx.x;
  for (int i = t; i < 1024; i += 256) w[i] = rw[i];
  __syncthreads();
  int n = blockIdx.x * 32 + (t >> 3);
  int k = t & 7;
  const __half2* hr = h + (size_t)n * 64;
  float acc = rb[k];
#pragma unroll 4
  for (int j = 0; j < 64; ++j) {
    float2 hv = __half22float2(hr[j]);
    acc += hv.x * w[(2 * j) * 8 + k] + hv.y * w[(2 * j + 1) * 8 + k];
  }
  o8[(size_t)n * 8 + k] = mish_f(acc);
}

// ---- fc1 split-K: z += feats[g, kc:kc+128] @ w[kc:kc+128, :] -------------
__global__ void k_fc1_init(const float* __restrict__ b, float* __restrict__ z) {
  int i = blockIdx.x * blockDim.x + threadIdx.x;
  if (i < 128 * 400) z[i] = b[i % 400];
}

__global__ __launch_bounds__(448) void k_fc1(const float* __restrict__ feats, const float* __restrict__ w,
                                             float* __restrict__ z) {
  __shared__ float fs[8][128];
  int t = threadIdx.x;
  int kc = blockIdx.x * 128;
  int g0 = blockIdx.y * 8;
  for (int i = t; i < 1024; i += 448) {
    int g = i >> 7, k = i & 127;
    fs[g][k] = feats[(size_t)(g0 + g) * 3200 + kc + k];
  }
  __syncthreads();
  if (t < 400) {
    float a[8];
#pragma unroll
    for (int g = 0; g < 8; ++g) a[g] = 0.0f;
    for (int k = 0; k < 128; ++k) {
      float wv = w[(size_t)(kc + k) * 400 + t];
#pragma unroll
      for (int g = 0; g < 8; ++g) a[g] += fs[g][k] * wv;
    }
#pragma unroll
    for (int g = 0; g < 8; ++g) atomicAdd(&z[(size_t)(g0 + g) * 400 + t], a[g]);
  }
}

// ---- batchnorm stats: one block per feature, thread = batch element ------
__global__ __launch_bounds__(128) void k_bn(const float* __restrict__ z, const float* __restrict__ gamma,
                                            const float* __restrict__ beta, float* __restrict__ gs,
                                            float* __restrict__ gb) {
  int j = blockIdx.x;
  int b = threadIdx.x;
  float v = z[b * 400 + j];
  float s = v, s2 = v * v;
#pragma unroll
  for (int off = 1; off < 64; off <<= 1) {
    s += __shfl_xor(s, off);
    s2 += __shfl_xor(s2, off);
  }
  __shared__ float ls[2], ls2[2];
  if ((b & 63) == 0) {
    ls[b >> 6] = s;
    ls2[b >> 6] = s2;
  }
  __syncthreads();
  if (b == 0) {
    float mu = (ls[0] + ls[1]) * (1.0f / 128.0f);
    float var = (ls2[0] + ls2[1]) * (1.0f / 128.0f) - mu * mu;
    float rs = rsqrtf(var + 1e-5f);
    float g = gamma[j] * rs;
    gs[j] = g;
    gb[j] = beta[j] - mu * g;
  }
}

// ---- fc2: one block per graph, block-reduce over j -----------------------
__global__ __launch_bounds__(256) void k_fc2(const float* __restrict__ z, const float* __restrict__ gs,
                                             const float* __restrict__ gb, const float* __restrict__ w2,
                                             const float* __restrict__ b2, float* __restrict__ out) {
  int bg = blockIdx.x;
  int t = threadIdx.x;
  float a0 = 0.f, a1 = 0.f;
  for (int j = t; j < 400; j += 256) {
    float zn = z[bg * 400 + j] * gs[j] + gb[j];
    float m = mish_f(zn);
    a0 += m * w2[j * 2];
    a1 += m * w2[j * 2 + 1];
  }
#pragma unroll
  for (int off = 1; off < 64; off <<= 1) {
    a0 += __shfl_xor(a0, off);
    a1 += __shfl_xor(a1, off);
  }
  __shared__ float s0[4], s1[4];
  if ((t & 63) == 0) {
    s0[t >> 6] = a0;
    s1[t >> 6] = a1;
  }
  __syncthreads();
  if (t == 0) {
    out[bg * 2 + 0] = b2[0] + s0[0] + s0[1] + s0[2] + s0[3];
    out[bg * 2 + 1] = b2[1] + s1[0] + s1[1] + s1[2] + s1[3];
  }
}

extern "C" void kernel_launch(void* const* d_in, const int* in_sizes, int n_in,
                              void* d_out, int out_size, void* d_ws, size_t ws_size,
                              hipStream_t stream) {
  (void)in_sizes; (void)n_in; (void)out_size; (void)ws_size;
  const float* x   = (const float*)d_in[0];
  const int*   ei  = (const int*)d_in[1];
  const float* ew  = (const float*)d_in[2];
  const float* c1w = (const float*)d_in[4];
  const float* c1b = (const float*)d_in[5];
  const float* c2w = (const float*)d_in[6];
  const float* c2b = (const float*)d_in[7];
  const float* rw  = (const float*)d_in[8];
  const float* rb  = (const float*)d_in[9];
  const float* f1w = (const float*)d_in[10];
  const float* f1b = (const float*)d_in[11];
  const float* bng = (const float*)d_in[12];
  const float* bnb = (const float*)d_in[13];
  const float* f2w = (const float*)d_in[14];
  const float* f2b = (const float*)d_in[15];
  float* out = (float*)d_out;

  char* ws = (char*)d_ws;
  size_t off = 0;
  auto alloc = [&](size_t bytes) {
    void* p = ws + off;
    off = (off + bytes + 255) & ~(size_t)255;
    return p;
  };
  unsigned long long* acc64 = (unsigned long long*)alloc((size_t)NN * 8);
  float* dinv   = (float*)alloc((size_t)NN * 4);
  int*   cnt    = (int*)alloc((size_t)NN * 4);
  int*   rowptr = (int*)alloc((size_t)(NN + 1) * 4);
  int*   rank   = (int*)alloc((size_t)NE * 4);
  int*   bsum   = (int*)alloc(200 * 4);
  int*   boff   = (int*)alloc(200 * 4);
  int2*  csr    = (int2*)alloc((size_t)NE * 8);
  __half* A1    = (__half*)alloc((size_t)NN * F * 2);  // gemm out (fp16)
  __half* B1    = (__half*)alloc((size_t)NN * F * 2);  // agg out (fp16)
  _Float16* Wt1 = (_Float16*)alloc((size_t)400 * 128 * 2);
  _Float16* Wt2 = (_Float16*)alloc((size_t)128 * 128 * 2);
  float* o8     = (float*)alloc((size_t)NN * 8 * 4);
  float* z      = (float*)alloc((size_t)128 * 400 * 4);
  float* gs     = (float*)alloc(400 * 4);
  float* gb     = (float*)alloc(400 * 4);

  hipMemsetAsync(acc64, 0, (size_t)NN * 8, stream);

  k_prep_w<<<(400 * 128 + 255) / 256, 256, 0, stream>>>(c1w, Wt1, 400);
  k_prep_w<<<(128 * 128 + 255) / 256, 256, 0, stream>>>(c2w, Wt2, 128);
  k_edge_cnt<<<(NE + 255) / 256, 256, 0, stream>>>(ei, ew, acc64, rank);
  k_dinv<<<(NN + 255) / 256, 256, 0, stream>>>(acc64, dinv, cnt);
  k_scan1<<<NN / 256, 256, 0, stream>>>(cnt, bsum);
  k_scan2<<<1, 256, 0, stream>>>(bsum, boff, rowptr);
  k_scan3<<<NN / 256, 256, 0, stream>>>(cnt, boff, rowptr);
  k_fill<<<(NE + 255) / 256, 256, 0, stream>>>(ei, ew, dinv, rowptr, rank, csr);

  // conv1: h = x@W1 (MFMA, fp16 out) ; agg+bias+mish (fp16 out)
  k_gemm16<true><<<NN / 128, 256, 0, stream>>>(x, Wt1, A1, 400);
  k_agg<<<NN / 4, 256, 0, stream>>>((const __half2*)A1, rowptr, csr, dinv, c1b, (__half2*)B1);
  // conv2
  k_gemm16<false><<<NN / 128, 256, 0, stream>>>(B1, Wt2, A1, 128);
  k_agg<<<NN / 4, 256, 0, stream>>>((const __half2*)A1, rowptr, csr, dinv, c2b, (__half2*)B1);
  // readout -> feats (o8 flat IS feats[128][3200])
  k_ro<<<NN / 32, 256, 0, stream>>>((const __half2*)B1, rw, rb, o8);
  k_fc1_init<<<(128 * 400 + 255) / 256, 256, 0, stream>>>(f1b, z);
  {
    dim3 g(25, 16);
    k_fc1<<<g, 448, 0, stream>>>(o8, f1w, z);
  }
  k_bn<<<400, 128, 0, stream>>>(z, bng, bnb, gs, gb);
  k_fc2<<<128, 256, 0, stream>>>(z, gs, gb, f2w, f2b, out);
}